// Round 6
// baseline (994.510 us; speedup 1.0000x reference)
//
#include <hip/hip_runtime.h>
#include <hip/hip_bf16.h>
#include <math.h>

#define NN 100000
#define EE 400000
#define KD 2
#define DD 256
#define ATTD 64
#define LL 3
#define HH1 128
#define HH2 64
#define EPSV 1e-5f
#define SLOPE 0.01f
#define KN (KD * NN)

typedef short short8 __attribute__((ext_vector_type(8)));
typedef float floatx4 __attribute__((ext_vector_type(4)));
typedef unsigned int u32x4 __attribute__((ext_vector_type(4)));
typedef unsigned short u16;
typedef unsigned int u32;
typedef unsigned long long u64;

__device__ __forceinline__ u16 f2bf(float f) {
    u32 u = __float_as_uint(f);
    return (u16)((u + 0x7fffu + ((u >> 16) & 1u)) >> 16);
}
__device__ __forceinline__ float bf2f(u16 h) {
    return __uint_as_float((u32)h << 16);
}

// ---------------- BatchNorm ----------------
__global__ void bn_stats(const float* __restrict__ x, float* __restrict__ sums) {
    int d = threadIdx.x;
    int r0 = blockIdx.x * 125;
    float s = 0.f, sq = 0.f;
    for (int r = r0; r < r0 + 125; ++r) {
        float v = x[(size_t)r * DD + d];
        s += v; sq += v * v;
    }
    atomicAdd(&sums[d], s);
    atomicAdd(&sums[DD + d], sq);
}

// writes h as pre-split bf16 hi/lo planes
__global__ void bn_apply(const float* __restrict__ x, const float* __restrict__ sums,
                         const float* __restrict__ gamma, const float* __restrict__ beta,
                         u16* __restrict__ h_hi, u16* __restrict__ h_lo) {
    size_t i = (size_t)blockIdx.x * blockDim.x + threadIdx.x;
    const float inv_n = 1.f / NN;
    int dq = (int)(i & 63) * 4;
    float4 xv = ((const float4*)x)[i];
    ushort4 hv, lv;
    float* xp = (float*)&xv;
    u16* hp = (u16*)&hv; u16* lp = (u16*)&lv;
#pragma unroll
    for (int j = 0; j < 4; ++j) {
        int d = dq + j;
        float mu = sums[d] * inv_n;
        float var = sums[DD + d] * inv_n - mu * mu;
        float inv = rsqrtf(var + EPSV);
        float v = (xp[j] - mu) * inv * gamma[d] + beta[d];
        u16 hb = f2bf(v);
        hp[j] = hb;
        lp[j] = f2bf(v - bf2f(hb));
    }
    ((ushort4*)h_hi)[i] = hv;
    ((ushort4*)h_lo)[i] = lv;
}

// ---------------- degree + CSR count (merged) ----------------
__global__ void deg_count(const int* __restrict__ ei, const float* __restrict__ w,
                          float* __restrict__ deg, int* __restrict__ counts) {
    int i = blockIdx.x * blockDim.x + threadIdx.x;
    if (i >= KD * EE) return;
    int k = i / EE, e = i - k * EE;
    int col = ei[(size_t)k * 2 * EE + EE + e];
    atomicAdd(&deg[k * NN + col], w[i]);
    atomicAdd(&counts[k * NN + col], 1);
}

__global__ void dinv_kernel(float* __restrict__ d) {
    int i = blockIdx.x * blockDim.x + threadIdx.x;
    if (i >= KD * NN) return;
    float v = d[i];
    d[i] = v > 0.f ? 1.f / sqrtf(v) : 0.f;
}

#define SCAN_NB ((KN + 255) / 256)   // 782
__global__ void scan_blocks(int* __restrict__ starts, int* __restrict__ bsums) {
    __shared__ int tmp[256];
    int t = threadIdx.x;
    int idx = blockIdx.x * 256 + t;
    int v = (idx < KN) ? starts[idx] : 0;
    tmp[t] = v;
    __syncthreads();
#pragma unroll
    for (int off = 1; off < 256; off <<= 1) {
        int s = (t >= off) ? tmp[t - off] : 0;
        __syncthreads();
        tmp[t] += s;
        __syncthreads();
    }
    if (idx < KN) starts[idx] = tmp[t] - v;          // exclusive
    if (t == 255) bsums[blockIdx.x] = tmp[255];      // block total
}

__global__ void scan_sums(int* __restrict__ bsums) {
    __shared__ int tmp[1024];
    int t = threadIdx.x;
    int v = (t < SCAN_NB) ? bsums[t] : 0;
    tmp[t] = v;
    __syncthreads();
#pragma unroll
    for (int off = 1; off < 1024; off <<= 1) {
        int s = (t >= off) ? tmp[t - off] : 0;
        __syncthreads();
        tmp[t] += s;
        __syncthreads();
    }
    if (t < SCAN_NB) bsums[t] = tmp[t] - v;          // exclusive
}

__global__ void scan_add(int* __restrict__ starts, const int* __restrict__ bsums) {
    int idx = blockIdx.x * 256 + threadIdx.x;
    if (idx < KN) starts[idx] += bsums[blockIdx.x];
}

__global__ void csr_fill(const int* __restrict__ ei, const float* __restrict__ w,
                         const float* __restrict__ dinv,
                         int* __restrict__ starts, int2* __restrict__ edata) {
    int i = blockIdx.x * blockDim.x + threadIdx.x;
    if (i >= KD * EE) return;
    int k = i / EE, e = i - k * EE;
    const int* eik = ei + (size_t)k * 2 * EE;
    int row = eik[e], col = eik[EE + e];
    float nv = dinv[k * NN + col] * w[i] * dinv[k * NN + row];
    int pos = atomicAdd(&starts[k * NN + col], 1);
    edata[pos] = make_int2(row, __float_as_int(nv));
}

// ---------------- gather aggregation v2: 2 nodes per wave (32-lane halves) ----------------
// Doubles memory-level parallelism per wave: two independent gather chains,
// 16 B/lane (uint4) keeps each row read a fully-coalesced 512 B segment.
__device__ __forceinline__ void fma_row8(float4& a0, float4& a1, uint4 w, float nv) {
    float2 f0 = __bfloat1622float2(*(const __hip_bfloat162*)&w.x);
    float2 f1 = __bfloat1622float2(*(const __hip_bfloat162*)&w.y);
    float2 f2 = __bfloat1622float2(*(const __hip_bfloat162*)&w.z);
    float2 f3 = __bfloat1622float2(*(const __hip_bfloat162*)&w.w);
    a0.x += nv * f0.x; a0.y += nv * f0.y; a0.z += nv * f1.x; a0.w += nv * f1.y;
    a1.x += nv * f2.x; a1.y += nv * f2.y; a1.z += nv * f3.x; a1.w += nv * f3.y;
}

__global__ __launch_bounds__(256) void gather_agg(
        const int* __restrict__ starts, const int2* __restrict__ edata,
        const u16* __restrict__ xw, u16* __restrict__ xs) {
    int wv = blockIdx.x * 4 + (threadIdx.x >> 6);
    int lane = threadIdx.x & 63;
    int half = lane >> 5, l32 = lane & 31;
    int widx = wv * 2 + half;            // KN = 200000 is exact for 25000 blocks
    if (widx >= KN) return;
    int begin = widx ? starts[widx - 1] : 0;
    int end = starts[widx];
    int deg = end - begin;
    float4 acc0 = make_float4(0.f, 0.f, 0.f, 0.f);
    float4 acc1 = make_float4(0.f, 0.f, 0.f, 0.f);

    // per-half prefetch of up to 32 edge records (deg>32 ~ never for Poisson(4))
    int2 ed = (l32 < deg) ? edata[begin + l32] : make_int2(0, 0);
    int dmain = deg > 32 ? 32 : deg;
    int base = half << 5;                // shuffle sources stay within own half

    int j = 0;
    for (; j + 4 <= dmain; j += 4) {
        int r0 = __shfl(ed.x, base + j),     r1 = __shfl(ed.x, base + j + 1);
        int r2 = __shfl(ed.x, base + j + 2), r3 = __shfl(ed.x, base + j + 3);
        float n0 = __int_as_float(__shfl(ed.y, base + j));
        float n1 = __int_as_float(__shfl(ed.y, base + j + 1));
        float n2 = __int_as_float(__shfl(ed.y, base + j + 2));
        float n3 = __int_as_float(__shfl(ed.y, base + j + 3));
        uint4 w0 = *(const uint4*)(xw + (size_t)r0 * DD + l32 * 8);
        uint4 w1 = *(const uint4*)(xw + (size_t)r1 * DD + l32 * 8);
        uint4 w2 = *(const uint4*)(xw + (size_t)r2 * DD + l32 * 8);
        uint4 w3 = *(const uint4*)(xw + (size_t)r3 * DD + l32 * 8);
        fma_row8(acc0, acc1, w0, n0);
        fma_row8(acc0, acc1, w1, n1);
        fma_row8(acc0, acc1, w2, n2);
        fma_row8(acc0, acc1, w3, n3);
    }
    for (; j < dmain; ++j) {
        int r = __shfl(ed.x, base + j);
        float nv = __int_as_float(__shfl(ed.y, base + j));
        uint4 w = *(const uint4*)(xw + (size_t)r * DD + l32 * 8);
        fma_row8(acc0, acc1, w, nv);
    }
    for (int e = begin + 32; e < end; ++e) {     // rare fallback: deg > 32
        int2 ee = edata[e];
        float nv = __int_as_float(ee.y);
        uint4 w = *(const uint4*)(xw + (size_t)ee.x * DD + l32 * 8);
        fma_row8(acc0, acc1, w, nv);
    }

    u32x4 st;
    st.x = (u32)f2bf(acc0.x) | ((u32)f2bf(acc0.y) << 16);
    st.y = (u32)f2bf(acc0.z) | ((u32)f2bf(acc0.w) << 16);
    st.z = (u32)f2bf(acc1.x) | ((u32)f2bf(acc1.y) << 16);
    st.w = (u32)f2bf(acc1.z) | ((u32)f2bf(acc1.w) << 16);
    __builtin_nontemporal_store(st, (u32x4*)(xs + (size_t)widx * DD + l32 * 8));
}

// ---------------- merged weight convert+transpose for ALL weights ----------------
#define GCN_T (LL * DD * DD)                 // 196608
#define ATT_T (LL * KD * DD * ATTD)          // 98304
#define P1_T  (DD * HH1)                     // 32768
#define P2_T  (HH1 * HH2)                    // 8192
#define WC_TOTAL (GCN_T + ATT_T + P1_T + P2_T)
__device__ __forceinline__ void wconv1(const float* __restrict__ W, u16* __restrict__ Wt,
                                       int i, int Kd, int Nc) {
    int kk = i / Nc, n = i - kk * Nc;
    Wt[(size_t)n * Kd + kk] = f2bf(W[i]);
}
__global__ void wconv_all(const float* __restrict__ gcnW, u16* __restrict__ gcnWb,
                          const float* __restrict__ attW, u16* __restrict__ attWb,
                          const float* __restrict__ pW1, u16* __restrict__ pW1b,
                          const float* __restrict__ pW2, u16* __restrict__ pW2b) {
    int gid = blockIdx.x * 256 + threadIdx.x;
    if (gid >= WC_TOTAL) return;
    if (gid < GCN_T) {
        int l = gid >> 16, i = gid & 65535;
        wconv1(gcnW + (size_t)l * DD * DD, gcnWb + (size_t)l * DD * DD, i, DD, DD);
    } else if (gid < GCN_T + ATT_T) {
        int g = gid - GCN_T;
        int lk = g >> 14, i = g & 16383;
        wconv1(attW + (size_t)lk * DD * ATTD, attWb + (size_t)lk * ATTD * DD, i, DD, ATTD);
    } else if (gid < GCN_T + ATT_T + P1_T) {
        wconv1(pW1, pW1b, gid - (GCN_T + ATT_T), DD, HH1);
    } else {
        wconv1(pW2, pW2b, gid - (GCN_T + ATT_T + P1_T), HH1, HH2);
    }
}

// ---------------- fold gcn_b into attention bias ----------------
__global__ void att_bias_fold(const float* __restrict__ attW, const float* __restrict__ attb,
                              const float* __restrict__ gcnb, float* __restrict__ batt) {
    int lk = blockIdx.x;          // 0..5
    int a = threadIdx.x;          // 0..63
    int l = lk >> 1;
    const float* W = attW + (size_t)lk * DD * ATTD;
    const float* gb = gcnb + l * DD;
    float s = attb[lk * ATTD + a];
    for (int d = 0; d < DD; ++d) s += gb[d] * W[d * ATTD + a];
    batt[lk * ATTD + a] = s;
}

#define LDSP 40   // LDS row stride in u16 (32 + 8 pad)

// ---------------- MFMA GEMM, BM=64, 4 waves laid out 1x4 across columns ----------------
template<int BN_, int MODE, bool PRESPLIT, bool BIAS, int ACT>
__global__ __launch_bounds__(256) void gemm_mfma(
        const float* __restrict__ A,
        const u16* __restrict__ Ahi, const u16* __restrict__ Alo,
        const u16* __restrict__ Bt, const float* __restrict__ bias,
        float* __restrict__ Cf, u16* __restrict__ Cb,
        int M, int Kd, int Nc) {
    constexpr int JW = BN_ / 64;           // j-frags per wave (wave covers BN_/4 cols)
    __shared__ u16 AsHi[64 * LDSP];
    __shared__ u16 AsLo[64 * LDSP];
    __shared__ u16 Bs[BN_ * LDSP];

    const int tid = threadIdx.x;
    const int lane = tid & 63, wx = tid >> 6;      // wave id 0..3 across columns
    const int lane15 = lane & 15, quad = lane >> 4;
    const int bm = blockIdx.x * 64;
    const int bn = blockIdx.y * BN_;

    floatx4 acc[4][JW];
#pragma unroll
    for (int i = 0; i < 4; ++i)
#pragma unroll
        for (int j = 0; j < JW; ++j) acc[i][j] = (floatx4){0.f, 0.f, 0.f, 0.f};

    for (int k0 = 0; k0 < Kd; k0 += 32) {
        if constexpr (PRESPLIT) {
            {   // 64 rows x 32 u16 per plane = 256 uint4 each; 1 per thread
                int m = tid >> 2, ko = (tid & 3) << 3;
                uint4 vh = make_uint4(0, 0, 0, 0), vl = make_uint4(0, 0, 0, 0);
                if (bm + m < M) {
                    vh = *(const uint4*)(Ahi + (size_t)(bm + m) * Kd + k0 + ko);
                    vl = *(const uint4*)(Alo + (size_t)(bm + m) * Kd + k0 + ko);
                }
                *(uint4*)(void*)(AsHi + m * LDSP + ko) = vh;
                *(uint4*)(void*)(AsLo + m * LDSP + ko) = vl;
            }
        } else {
#pragma unroll
            for (int t = tid; t < 512; t += 256) {
                int m = t >> 3, k4 = (t & 7) << 2;
                float4 v = make_float4(0.f, 0.f, 0.f, 0.f);
                if (bm + m < M) v = *(const float4*)(A + (size_t)(bm + m) * Kd + k0 + k4);
                u16 h0 = f2bf(v.x), h1 = f2bf(v.y), h2 = f2bf(v.z), h3 = f2bf(v.w);
                *(ushort4*)(void*)(AsHi + m * LDSP + k4) = make_ushort4(h0, h1, h2, h3);
                u16 l0 = f2bf(v.x - bf2f(h0)), l1 = f2bf(v.y - bf2f(h1));
                u16 l2 = f2bf(v.z - bf2f(h2)), l3 = f2bf(v.w - bf2f(h3));
                *(ushort4*)(void*)(AsLo + m * LDSP + k4) = make_ushort4(l0, l1, l2, l3);
            }
        }
#pragma unroll
        for (int t = tid; t < BN_ * 4; t += 256) {
            int n = t >> 2, ko = (t & 3) << 3;
            uint4 w = *(const uint4*)(Bt + (size_t)(bn + n) * Kd + k0 + ko);
            *(uint4*)(void*)(Bs + n * LDSP + ko) = w;
        }
        __syncthreads();

        const u16* pA  = AsHi + lane15 * LDSP + quad * 8;
        const u16* pAl = AsLo + lane15 * LDSP + quad * 8;
        const u16* pB  = Bs + (wx * (BN_ / 4) + lane15) * LDSP + quad * 8;
        short8 b[JW];
#pragma unroll
        for (int j = 0; j < JW; ++j) b[j] = *(const short8*)(pB + j * 16 * LDSP);
#pragma unroll
        for (int i = 0; i < 4; ++i) {
            short8 a = *(const short8*)(pA + i * 16 * LDSP);
#pragma unroll
            for (int j = 0; j < JW; ++j)
                acc[i][j] = __builtin_amdgcn_mfma_f32_16x16x32_bf16(a, b[j], acc[i][j], 0, 0, 0);
        }
#pragma unroll
        for (int i = 0; i < 4; ++i) {
            short8 a = *(const short8*)(pAl + i * 16 * LDSP);
#pragma unroll
            for (int j = 0; j < JW; ++j)
                acc[i][j] = __builtin_amdgcn_mfma_f32_16x16x32_bf16(a, b[j], acc[i][j], 0, 0, 0);
        }
        __syncthreads();
    }

#pragma unroll
    for (int i = 0; i < 4; ++i) {
#pragma unroll
        for (int r = 0; r < 4; ++r) {
            int row = bm + i * 16 + quad * 4 + r;
            if (row >= M) continue;
#pragma unroll
            for (int j = 0; j < JW; ++j) {
                int col = bn + wx * (BN_ / 4) + j * 16 + lane15;
                float v = acc[i][j][r];
                if constexpr (BIAS) v += bias[col];
                if constexpr (ACT == 1) v = v > 0.f ? v : SLOPE * v;
                if constexpr (MODE == 0) Cf[(size_t)row * Nc + col] = v;
                else                     Cb[(size_t)row * Nc + col] = f2bf(v);
            }
        }
    }
}

// ---------------- fused attention v4: no xs staging; VGPR-rich schedule ----------------
// (256,3): cap ~168 VGPR so bf[8][2] (64 VGPR) + acc (32) + an 8-deep A-load
// pipeline stay resident. Round-3's (256,4) crushed it to 48 VGPR -> B-frag
// reloads + serialized A loads (2.5 TB/s). Grid is ~6 blocks/CU so occupancy
// beyond 3 blocks/CU buys nothing; MLP per wave is what matters.
__global__ __launch_bounds__(256, 3) void att_combine(
        const u16* __restrict__ xs, const u16* __restrict__ Bt,
        const float* __restrict__ batt, const float* __restrict__ qv,
        const float* __restrict__ gcnb,
        u16* __restrict__ h_hi, u16* __restrict__ h_lo) {
    __shared__ float simbuf[KD][2][64];

    const int tid = threadIdx.x;
    const int lane = tid & 63, waveid = tid >> 6;
    const int kw = waveid >> 1, ch = waveid & 1;
    const int lane15 = lane & 15, quad = lane >> 4;
    const int bm = blockIdx.x * 64;

    // preload all B fragments into registers (global reads, L2-hot weights)
    short8 bf[8][2];
#pragma unroll
    for (int t = 0; t < 8; ++t)
#pragma unroll
        for (int j = 0; j < 2; ++j) {
            int col = ch * 32 + j * 16 + lane15;
            bf[t][j] = *(const short8*)(Bt + (size_t)kw * ATTD * DD +
                                        (size_t)col * DD + t * 32 + quad * 8);
        }

    floatx4 acc[4][2];
#pragma unroll
    for (int i = 0; i < 4; ++i)
#pragma unroll
        for (int j = 0; j < 2; ++j) acc[i][j] = (floatx4){0.f, 0.f, 0.f, 0.f};

    // A fragments from global: per row-stripe, batch all 8 16-B loads into
    // registers first (8 in flight), then the 16 dependent MFMAs.
#pragma unroll
    for (int i = 0; i < 4; ++i) {
        int row = bm + i * 16 + lane15;
        row = row < NN ? row : 0;
        const u16* pa = xs + ((size_t)kw * NN + row) * DD + quad * 8;
        short8 a[8];
#pragma unroll
        for (int t = 0; t < 8; ++t) a[t] = *(const short8*)(pa + t * 32);
#pragma unroll
        for (int t = 0; t < 8; ++t) {
            acc[i][0] = __builtin_amdgcn_mfma_f32_16x16x32_bf16(a[t], bf[t][0], acc[i][0], 0, 0, 0);
            acc[i][1] = __builtin_amdgcn_mfma_f32_16x16x32_bf16(a[t], bf[t][1], acc[i][1], 0, 0, 0);
        }
    }

    // sim: per row sum over this wave's 32 cols of tanh(v+batt)*q
#pragma unroll
    for (int i = 0; i < 4; ++i) {
#pragma unroll
        for (int r = 0; r < 4; ++r) {
            float p = 0.f;
#pragma unroll
            for (int j = 0; j < 2; ++j) {
                int col = ch * 32 + j * 16 + lane15;
                float v = acc[i][j][r] + batt[kw * ATTD + col];
                float ex = __expf(2.f * v);
                float th = 1.f - 2.f / (ex + 1.f);     // tanh, inf-safe
                p += th * qv[kw * ATTD + col];
            }
            p += __shfl_xor(p, 1, 64);
            p += __shfl_xor(p, 2, 64);
            p += __shfl_xor(p, 4, 64);
            p += __shfl_xor(p, 8, 64);
            if (lane15 == 0) simbuf[kw][ch][i * 16 + quad * 4 + r] = p;
        }
    }
    __syncthreads();

    // combine: 64 rows x 32 16B-chunks / 256 threads = 8 items; xs from global (coalesced)
#pragma unroll 4
    for (int it = 0; it < 8; ++it) {
        int item = tid + it * 256;
        int row = item >> 5, c8 = item & 31;
        int grow = bm + row;
        if (grow >= NN) continue;
        float s0 = simbuf[0][0][row] + simbuf[0][1][row];
        float s1 = simbuf[1][0][row] + simbuf[1][1][row];
        float m = fmaxf(s0, s1);
        float e0 = __expf(s0 - m), e1 = __expf(s1 - m);
        float inv = 1.f / (e0 + e1);
        float a0 = e0 * inv, a1 = e1 * inv;
        uint4 x0 = *(const uint4*)(xs + (size_t)grow * DD + c8 * 8);
        uint4 x1 = *(const uint4*)(xs + ((size_t)NN + grow) * DD + c8 * 8);
        const float* bp = gcnb + c8 * 8;
        uint4 hiw, low;
        u16* hp = (u16*)&hiw; u16* lp = (u16*)&low;
        const u32* xp0 = (const u32*)&x0; const u32* xp1 = (const u32*)&x1;
#pragma unroll
        for (int j = 0; j < 4; ++j) {
            float2 f0 = __bfloat1622float2(*(const __hip_bfloat162*)&xp0[j]);
            float2 f1 = __bfloat1622float2(*(const __hip_bfloat162*)&xp1[j]);
            float ra = fmaxf(0.f, a0 * f0.x + a1 * f1.x + bp[2 * j]);
            float rb = fmaxf(0.f, a0 * f0.y + a1 * f1.y + bp[2 * j + 1]);
            u16 ha = f2bf(ra), hb = f2bf(rb);
            hp[2 * j] = ha; hp[2 * j + 1] = hb;
            lp[2 * j] = f2bf(ra - bf2f(ha));
            lp[2 * j + 1] = f2bf(rb - bf2f(hb));
        }
        *(uint4*)(h_hi + (size_t)grow * DD + c8 * 8) = hiw;
        *(uint4*)(h_lo + (size_t)grow * DD + c8 * 8) = low;
    }
}

extern "C" void kernel_launch(void* const* d_in, const int* in_sizes, int n_in,
                              void* d_out, int out_size, void* d_ws, size_t ws_size,
                              hipStream_t stream) {
    const float* x     = (const float*)d_in[0];
    const int*   ei    = (const int*)d_in[1];
    const float* ew    = (const float*)d_in[2];
    const float* gamma = (const float*)d_in[3];
    const float* beta  = (const float*)d_in[4];
    const float* gcn_W = (const float*)d_in[5];
    const float* gcn_b = (const float*)d_in[6];
    const float* att_W = (const float*)d_in[7];
    const float* att_b = (const float*)d_in[8];
    const float* att_q = (const float*)d_in[9];
    const float* pW1   = (const float*)d_in[10];
    const float* pb1   = (const float*)d_in[11];
    const float* pW2   = (const float*)d_in[12];
    const float* pb2   = (const float*)d_in[13];
    float* out = (float*)d_out;

    char* wsb = (char*)d_ws;
    size_t off = 0;
    auto alloc = [&](size_t bytes) -> void* {
        void* p = wsb + off;
        off += (bytes + 255) & ~(size_t)255;
        return p;
    };
    u16*   xs    = (u16*)alloc((size_t)KD * NN * DD * 2);     // 102.4 MB (bf16)
    u16*   h_hi  = (u16*)alloc((size_t)NN * DD * 2);          // 51.2 MB
    u16*   h_lo  = (u16*)alloc((size_t)NN * DD * 2);          // 51.2 MB
    u16*   xw    = (u16*)alloc((size_t)NN * DD * 2);          // 51.2 MB
    float* p1tmp = (float*)xw;                                // N*H1*4, exact reuse
    float* dinv  = (float*)alloc((size_t)KN * 4);             // adjacent to starts
    int*   starts= (int*)alloc(((size_t)KN + 1) * 4);
    int2*  edata = (int2*)alloc((size_t)KD * EE * 8);         // 6.4 MB
    float* bnsums= (float*)alloc(2 * DD * 4);
    u16*   gcnWb = (u16*)alloc((size_t)LL * DD * DD * 2);
    u16*   attWb = (u16*)alloc((size_t)LL * KD * ATTD * DD * 2);
    u16*   pW1b  = (u16*)alloc((size_t)HH1 * DD * 2);
    u16*   pW2b  = (u16*)alloc((size_t)HH2 * HH1 * 2);
    float* batt  = (float*)alloc((size_t)LL * KD * ATTD * 4);
    int*   bsums = (int*)alloc((size_t)SCAN_NB * 4);

    // ---- setup: all weight converts in ONE kernel + att bias fold ----
    wconv_all<<<(WC_TOTAL + 255) / 256, 256, 0, stream>>>(
        gcn_W, gcnWb, att_W, attWb, pW1, pW1b, pW2, pW2b);
    att_bias_fold<<<LL * KD, ATTD, 0, stream>>>(att_W, att_b, gcn_b, batt);

    // ---- BatchNorm -> h (pre-split) ----
    hipMemsetAsync(bnsums, 0, 2 * DD * 4, stream);
    bn_stats<<<800, 256, 0, stream>>>(x, bnsums);
    bn_apply<<<25000, 256, 0, stream>>>(x, bnsums, gamma, beta, h_hi, h_lo);

    // ---- degree / CSR (layer-invariant); dinv+starts zeroed in one memset ----
    hipMemsetAsync(dinv, 0, (size_t)KN * 4 + ((size_t)KN + 1) * 4, stream);
    deg_count<<<(KD * EE + 255) / 256, 256, 0, stream>>>(ei, ew, dinv, starts);
    dinv_kernel<<<(KN + 255) / 256, 256, 0, stream>>>(dinv);
    scan_blocks<<<SCAN_NB, 256, 0, stream>>>(starts, bsums);
    scan_sums<<<1, 1024, 0, stream>>>(bsums);
    scan_add<<<SCAN_NB, 256, 0, stream>>>(starts, bsums);
    csr_fill<<<(KD * EE + 255) / 256, 256, 0, stream>>>(ei, ew, dinv, starts, edata);

    const int MB64 = (NN + 63) / 64;     // 1563
    for (int l = 0; l < LL; ++l) {
        // xw(bf16) = h @ gcn_W[l] — BM=64 x BN=256, copy-only staging
        gemm_mfma<256, 1, true, false, 0><<<dim3(MB64, 1), 256, 0, stream>>>(
            nullptr, h_hi, h_lo, gcnWb + (size_t)l * DD * DD, nullptr,
            nullptr, xw, NN, DD, DD);
        gather_agg<<<(KN + 7) / 8, 256, 0, stream>>>(starts, edata, xw, xs);
        att_combine<<<MB64, 256, 0, stream>>>(
            xs, attWb + (size_t)l * KD * ATTD * DD,
            batt + (size_t)l * KD * ATTD, att_q + (size_t)l * KD * ATTD,
            gcn_b + l * DD, h_hi, h_lo);
    }

    // ---- projection head ----
    gemm_mfma<128, 0, true, true, 1><<<dim3(MB64, 1), 256, 0, stream>>>(
        nullptr, h_hi, h_lo, pW1b, pb1, p1tmp, nullptr, NN, DD, HH1);
    gemm_mfma<64, 0, false, true, 1><<<dim3(MB64, 1), 256, 0, stream>>>(
        p1tmp, nullptr, nullptr, pW2b, pb2, out, nullptr, NN, HH1, HH2);
}

// Round 7
// 992.105 us; speedup vs baseline: 1.0024x; 1.0024x over previous
//
#include <hip/hip_runtime.h>
#include <hip/hip_bf16.h>
#include <math.h>

#define NN 100000
#define EE 400000
#define KD 2
#define DD 256
#define ATTD 64
#define LL 3
#define HH1 128
#define HH2 64
#define EPSV 1e-5f
#define SLOPE 0.01f
#define KN (KD * NN)

typedef short short8 __attribute__((ext_vector_type(8)));
typedef float floatx4 __attribute__((ext_vector_type(4)));
typedef unsigned int u32x4 __attribute__((ext_vector_type(4)));
typedef unsigned short u16;
typedef unsigned int u32;
typedef unsigned long long u64;

__device__ __forceinline__ u16 f2bf(float f) {
    u32 u = __float_as_uint(f);
    return (u16)((u + 0x7fffu + ((u >> 16) & 1u)) >> 16);
}
__device__ __forceinline__ float bf2f(u16 h) {
    return __uint_as_float((u32)h << 16);
}

// ---------------- BatchNorm ----------------
__global__ void bn_stats(const float* __restrict__ x, float* __restrict__ sums) {
    int d = threadIdx.x;
    int r0 = blockIdx.x * 125;
    float s = 0.f, sq = 0.f;
    for (int r = r0; r < r0 + 125; ++r) {
        float v = x[(size_t)r * DD + d];
        s += v; sq += v * v;
    }
    atomicAdd(&sums[d], s);
    atomicAdd(&sums[DD + d], sq);
}

// writes h as pre-split bf16 hi/lo planes
__global__ void bn_apply(const float* __restrict__ x, const float* __restrict__ sums,
                         const float* __restrict__ gamma, const float* __restrict__ beta,
                         u16* __restrict__ h_hi, u16* __restrict__ h_lo) {
    size_t i = (size_t)blockIdx.x * blockDim.x + threadIdx.x;
    const float inv_n = 1.f / NN;
    int dq = (int)(i & 63) * 4;
    float4 xv = ((const float4*)x)[i];
    ushort4 hv, lv;
    float* xp = (float*)&xv;
    u16* hp = (u16*)&hv; u16* lp = (u16*)&lv;
#pragma unroll
    for (int j = 0; j < 4; ++j) {
        int d = dq + j;
        float mu = sums[d] * inv_n;
        float var = sums[DD + d] * inv_n - mu * mu;
        float inv = rsqrtf(var + EPSV);
        float v = (xp[j] - mu) * inv * gamma[d] + beta[d];
        u16 hb = f2bf(v);
        hp[j] = hb;
        lp[j] = f2bf(v - bf2f(hb));
    }
    ((ushort4*)h_hi)[i] = hv;
    ((ushort4*)h_lo)[i] = lv;
}

// ---------------- degree + CSR count (merged) ----------------
__global__ void deg_count(const int* __restrict__ ei, const float* __restrict__ w,
                          float* __restrict__ deg, int* __restrict__ counts) {
    int i = blockIdx.x * blockDim.x + threadIdx.x;
    if (i >= KD * EE) return;
    int k = i / EE, e = i - k * EE;
    int col = ei[(size_t)k * 2 * EE + EE + e];
    atomicAdd(&deg[k * NN + col], w[i]);
    atomicAdd(&counts[k * NN + col], 1);
}

__global__ void dinv_kernel(float* __restrict__ d) {
    int i = blockIdx.x * blockDim.x + threadIdx.x;
    if (i >= KD * NN) return;
    float v = d[i];
    d[i] = v > 0.f ? 1.f / sqrtf(v) : 0.f;
}

#define SCAN_NB ((KN + 255) / 256)   // 782
__global__ void scan_blocks(int* __restrict__ starts, int* __restrict__ bsums) {
    __shared__ int tmp[256];
    int t = threadIdx.x;
    int idx = blockIdx.x * 256 + t;
    int v = (idx < KN) ? starts[idx] : 0;
    tmp[t] = v;
    __syncthreads();
#pragma unroll
    for (int off = 1; off < 256; off <<= 1) {
        int s = (t >= off) ? tmp[t - off] : 0;
        __syncthreads();
        tmp[t] += s;
        __syncthreads();
    }
    if (idx < KN) starts[idx] = tmp[t] - v;          // exclusive
    if (t == 255) bsums[blockIdx.x] = tmp[255];      // block total
}

__global__ void scan_sums(int* __restrict__ bsums) {
    __shared__ int tmp[1024];
    int t = threadIdx.x;
    int v = (t < SCAN_NB) ? bsums[t] : 0;
    tmp[t] = v;
    __syncthreads();
#pragma unroll
    for (int off = 1; off < 1024; off <<= 1) {
        int s = (t >= off) ? tmp[t - off] : 0;
        __syncthreads();
        tmp[t] += s;
        __syncthreads();
    }
    if (t < SCAN_NB) bsums[t] = tmp[t] - v;          // exclusive
}

__global__ void scan_add(int* __restrict__ starts, const int* __restrict__ bsums) {
    int idx = blockIdx.x * 256 + threadIdx.x;
    if (idx < KN) starts[idx] += bsums[blockIdx.x];
}

__global__ void csr_fill(const int* __restrict__ ei, const float* __restrict__ w,
                         const float* __restrict__ dinv,
                         int* __restrict__ starts, int2* __restrict__ edata) {
    int i = blockIdx.x * blockDim.x + threadIdx.x;
    if (i >= KD * EE) return;
    int k = i / EE, e = i - k * EE;
    const int* eik = ei + (size_t)k * 2 * EE;
    int row = eik[e], col = eik[EE + e];
    float nv = dinv[k * NN + col] * w[i] * dinv[k * NN + row];
    int pos = atomicAdd(&starts[k * NN + col], 1);
    edata[pos] = make_int2(row, __float_as_int(nv));
}

// ---------------- gather aggregation v2: 2 nodes per wave (32-lane halves) ----------------
// Doubles memory-level parallelism per wave: two independent gather chains,
// 16 B/lane (uint4) keeps each row read a fully-coalesced 512 B segment.
__device__ __forceinline__ void fma_row8(float4& a0, float4& a1, uint4 w, float nv) {
    float2 f0 = __bfloat1622float2(*(const __hip_bfloat162*)&w.x);
    float2 f1 = __bfloat1622float2(*(const __hip_bfloat162*)&w.y);
    float2 f2 = __bfloat1622float2(*(const __hip_bfloat162*)&w.z);
    float2 f3 = __bfloat1622float2(*(const __hip_bfloat162*)&w.w);
    a0.x += nv * f0.x; a0.y += nv * f0.y; a0.z += nv * f1.x; a0.w += nv * f1.y;
    a1.x += nv * f2.x; a1.y += nv * f2.y; a1.z += nv * f3.x; a1.w += nv * f3.y;
}

__global__ __launch_bounds__(256) void gather_agg(
        const int* __restrict__ starts, const int2* __restrict__ edata,
        const u16* __restrict__ xw, u16* __restrict__ xs) {
    int wv = blockIdx.x * 4 + (threadIdx.x >> 6);
    int lane = threadIdx.x & 63;
    int half = lane >> 5, l32 = lane & 31;
    int widx = wv * 2 + half;            // KN = 200000 is exact for 25000 blocks
    if (widx >= KN) return;
    int begin = widx ? starts[widx - 1] : 0;
    int end = starts[widx];
    int deg = end - begin;
    float4 acc0 = make_float4(0.f, 0.f, 0.f, 0.f);
    float4 acc1 = make_float4(0.f, 0.f, 0.f, 0.f);

    // per-half prefetch of up to 32 edge records (deg>32 ~ never for Poisson(4))
    int2 ed = (l32 < deg) ? edata[begin + l32] : make_int2(0, 0);
    int dmain = deg > 32 ? 32 : deg;
    int base = half << 5;                // shuffle sources stay within own half

    int j = 0;
    for (; j + 4 <= dmain; j += 4) {
        int r0 = __shfl(ed.x, base + j),     r1 = __shfl(ed.x, base + j + 1);
        int r2 = __shfl(ed.x, base + j + 2), r3 = __shfl(ed.x, base + j + 3);
        float n0 = __int_as_float(__shfl(ed.y, base + j));
        float n1 = __int_as_float(__shfl(ed.y, base + j + 1));
        float n2 = __int_as_float(__shfl(ed.y, base + j + 2));
        float n3 = __int_as_float(__shfl(ed.y, base + j + 3));
        uint4 w0 = *(const uint4*)(xw + (size_t)r0 * DD + l32 * 8);
        uint4 w1 = *(const uint4*)(xw + (size_t)r1 * DD + l32 * 8);
        uint4 w2 = *(const uint4*)(xw + (size_t)r2 * DD + l32 * 8);
        uint4 w3 = *(const uint4*)(xw + (size_t)r3 * DD + l32 * 8);
        fma_row8(acc0, acc1, w0, n0);
        fma_row8(acc0, acc1, w1, n1);
        fma_row8(acc0, acc1, w2, n2);
        fma_row8(acc0, acc1, w3, n3);
    }
    for (; j < dmain; ++j) {
        int r = __shfl(ed.x, base + j);
        float nv = __int_as_float(__shfl(ed.y, base + j));
        uint4 w = *(const uint4*)(xw + (size_t)r * DD + l32 * 8);
        fma_row8(acc0, acc1, w, nv);
    }
    for (int e = begin + 32; e < end; ++e) {     // rare fallback: deg > 32
        int2 ee = edata[e];
        float nv = __int_as_float(ee.y);
        uint4 w = *(const uint4*)(xw + (size_t)ee.x * DD + l32 * 8);
        fma_row8(acc0, acc1, w, nv);
    }

    u32x4 st;
    st.x = (u32)f2bf(acc0.x) | ((u32)f2bf(acc0.y) << 16);
    st.y = (u32)f2bf(acc0.z) | ((u32)f2bf(acc0.w) << 16);
    st.z = (u32)f2bf(acc1.x) | ((u32)f2bf(acc1.y) << 16);
    st.w = (u32)f2bf(acc1.z) | ((u32)f2bf(acc1.w) << 16);
    __builtin_nontemporal_store(st, (u32x4*)(xs + (size_t)widx * DD + l32 * 8));
}

// ---------------- merged weight convert+transpose for ALL weights ----------------
#define GCN_T (LL * DD * DD)                 // 196608
#define ATT_T (LL * KD * DD * ATTD)          // 98304
#define P1_T  (DD * HH1)                     // 32768
#define P2_T  (HH1 * HH2)                    // 8192
#define WC_TOTAL (GCN_T + ATT_T + P1_T + P2_T)
__device__ __forceinline__ void wconv1(const float* __restrict__ W, u16* __restrict__ Wt,
                                       int i, int Kd, int Nc) {
    int kk = i / Nc, n = i - kk * Nc;
    Wt[(size_t)n * Kd + kk] = f2bf(W[i]);
}
__global__ void wconv_all(const float* __restrict__ gcnW, u16* __restrict__ gcnWb,
                          const float* __restrict__ attW, u16* __restrict__ attWb,
                          const float* __restrict__ pW1, u16* __restrict__ pW1b,
                          const float* __restrict__ pW2, u16* __restrict__ pW2b) {
    int gid = blockIdx.x * 256 + threadIdx.x;
    if (gid >= WC_TOTAL) return;
    if (gid < GCN_T) {
        int l = gid >> 16, i = gid & 65535;
        wconv1(gcnW + (size_t)l * DD * DD, gcnWb + (size_t)l * DD * DD, i, DD, DD);
    } else if (gid < GCN_T + ATT_T) {
        int g = gid - GCN_T;
        int lk = g >> 14, i = g & 16383;
        wconv1(attW + (size_t)lk * DD * ATTD, attWb + (size_t)lk * ATTD * DD, i, DD, ATTD);
    } else if (gid < GCN_T + ATT_T + P1_T) {
        wconv1(pW1, pW1b, gid - (GCN_T + ATT_T), DD, HH1);
    } else {
        wconv1(pW2, pW2b, gid - (GCN_T + ATT_T + P1_T), HH1, HH2);
    }
}

// ---------------- fold gcn_b into attention bias ----------------
__global__ void att_bias_fold(const float* __restrict__ attW, const float* __restrict__ attb,
                              const float* __restrict__ gcnb, float* __restrict__ batt) {
    int lk = blockIdx.x;          // 0..5
    int a = threadIdx.x;          // 0..63
    int l = lk >> 1;
    const float* W = attW + (size_t)lk * DD * ATTD;
    const float* gb = gcnb + l * DD;
    float s = attb[lk * ATTD + a];
    for (int d = 0; d < DD; ++d) s += gb[d] * W[d * ATTD + a];
    batt[lk * ATTD + a] = s;
}

#define LDSP 40   // LDS row stride in u16 (32 + 8 pad)

// ---------------- MFMA GEMM, BM=64, 4 waves laid out 1x4 across columns ----------------
template<int BN_, int MODE, bool PRESPLIT, bool BIAS, int ACT>
__global__ __launch_bounds__(256) void gemm_mfma(
        const float* __restrict__ A,
        const u16* __restrict__ Ahi, const u16* __restrict__ Alo,
        const u16* __restrict__ Bt, const float* __restrict__ bias,
        float* __restrict__ Cf, u16* __restrict__ Cb,
        int M, int Kd, int Nc) {
    constexpr int JW = BN_ / 64;           // j-frags per wave (wave covers BN_/4 cols)
    __shared__ u16 AsHi[64 * LDSP];
    __shared__ u16 AsLo[64 * LDSP];
    __shared__ u16 Bs[BN_ * LDSP];

    const int tid = threadIdx.x;
    const int lane = tid & 63, wx = tid >> 6;      // wave id 0..3 across columns
    const int lane15 = lane & 15, quad = lane >> 4;
    const int bm = blockIdx.x * 64;
    const int bn = blockIdx.y * BN_;

    floatx4 acc[4][JW];
#pragma unroll
    for (int i = 0; i < 4; ++i)
#pragma unroll
        for (int j = 0; j < JW; ++j) acc[i][j] = (floatx4){0.f, 0.f, 0.f, 0.f};

    for (int k0 = 0; k0 < Kd; k0 += 32) {
        if constexpr (PRESPLIT) {
            {   // 64 rows x 32 u16 per plane = 256 uint4 each; 1 per thread
                int m = tid >> 2, ko = (tid & 3) << 3;
                uint4 vh = make_uint4(0, 0, 0, 0), vl = make_uint4(0, 0, 0, 0);
                if (bm + m < M) {
                    vh = *(const uint4*)(Ahi + (size_t)(bm + m) * Kd + k0 + ko);
                    vl = *(const uint4*)(Alo + (size_t)(bm + m) * Kd + k0 + ko);
                }
                *(uint4*)(void*)(AsHi + m * LDSP + ko) = vh;
                *(uint4*)(void*)(AsLo + m * LDSP + ko) = vl;
            }
        } else {
#pragma unroll
            for (int t = tid; t < 512; t += 256) {
                int m = t >> 3, k4 = (t & 7) << 2;
                float4 v = make_float4(0.f, 0.f, 0.f, 0.f);
                if (bm + m < M) v = *(const float4*)(A + (size_t)(bm + m) * Kd + k0 + k4);
                u16 h0 = f2bf(v.x), h1 = f2bf(v.y), h2 = f2bf(v.z), h3 = f2bf(v.w);
                *(ushort4*)(void*)(AsHi + m * LDSP + k4) = make_ushort4(h0, h1, h2, h3);
                u16 l0 = f2bf(v.x - bf2f(h0)), l1 = f2bf(v.y - bf2f(h1));
                u16 l2 = f2bf(v.z - bf2f(h2)), l3 = f2bf(v.w - bf2f(h3));
                *(ushort4*)(void*)(AsLo + m * LDSP + k4) = make_ushort4(l0, l1, l2, l3);
            }
        }
#pragma unroll
        for (int t = tid; t < BN_ * 4; t += 256) {
            int n = t >> 2, ko = (t & 3) << 3;
            uint4 w = *(const uint4*)(Bt + (size_t)(bn + n) * Kd + k0 + ko);
            *(uint4*)(void*)(Bs + n * LDSP + ko) = w;
        }
        __syncthreads();

        const u16* pA  = AsHi + lane15 * LDSP + quad * 8;
        const u16* pAl = AsLo + lane15 * LDSP + quad * 8;
        const u16* pB  = Bs + (wx * (BN_ / 4) + lane15) * LDSP + quad * 8;
        short8 b[JW];
#pragma unroll
        for (int j = 0; j < JW; ++j) b[j] = *(const short8*)(pB + j * 16 * LDSP);
#pragma unroll
        for (int i = 0; i < 4; ++i) {
            short8 a = *(const short8*)(pA + i * 16 * LDSP);
#pragma unroll
            for (int j = 0; j < JW; ++j)
                acc[i][j] = __builtin_amdgcn_mfma_f32_16x16x32_bf16(a, b[j], acc[i][j], 0, 0, 0);
        }
#pragma unroll
        for (int i = 0; i < 4; ++i) {
            short8 a = *(const short8*)(pAl + i * 16 * LDSP);
#pragma unroll
            for (int j = 0; j < JW; ++j)
                acc[i][j] = __builtin_amdgcn_mfma_f32_16x16x32_bf16(a, b[j], acc[i][j], 0, 0, 0);
        }
        __syncthreads();
    }

#pragma unroll
    for (int i = 0; i < 4; ++i) {
#pragma unroll
        for (int r = 0; r < 4; ++r) {
            int row = bm + i * 16 + quad * 4 + r;
            if (row >= M) continue;
#pragma unroll
            for (int j = 0; j < JW; ++j) {
                int col = bn + wx * (BN_ / 4) + j * 16 + lane15;
                float v = acc[i][j][r];
                if constexpr (BIAS) v += bias[col];
                if constexpr (ACT == 1) v = v > 0.f ? v : SLOPE * v;
                if constexpr (MODE == 0) Cf[(size_t)row * Nc + col] = v;
                else                     Cb[(size_t)row * Nc + col] = f2bf(v);
            }
        }
    }
}

// ---------------- fused attention v5: no xs staging; waves_per_eu(3,3) ----------------
// Round-6 lesson: __launch_bounds__(256,N) only sets a MIN-waves guarantee; the
// AMDGPU scheduler still targets MAX occupancy and minimized to 48 VGPR (bf[]
// reloaded in-loop, serialized A loads, 2.6 TB/s). amdgpu_waves_per_eu(3,3)
// caps target occupancy at 3 waves/EU (= what the grid supplies anyway, occ 37%),
// giving regalloc a ~170 VGPR budget -> bf[8][2] resident + 8-deep A pipeline.
__global__ __launch_bounds__(256)
__attribute__((amdgpu_waves_per_eu(3, 3)))
void att_combine(
        const u16* __restrict__ xs, const u16* __restrict__ Bt,
        const float* __restrict__ batt, const float* __restrict__ qv,
        const float* __restrict__ gcnb,
        u16* __restrict__ h_hi, u16* __restrict__ h_lo) {
    __shared__ float simbuf[KD][2][64];

    const int tid = threadIdx.x;
    const int lane = tid & 63, waveid = tid >> 6;
    const int kw = waveid >> 1, ch = waveid & 1;
    const int lane15 = lane & 15, quad = lane >> 4;
    const int bm = blockIdx.x * 64;

    // preload all B fragments into registers (global reads, L2-hot weights)
    short8 bf[8][2];
#pragma unroll
    for (int t = 0; t < 8; ++t)
#pragma unroll
        for (int j = 0; j < 2; ++j) {
            int col = ch * 32 + j * 16 + lane15;
            bf[t][j] = *(const short8*)(Bt + (size_t)kw * ATTD * DD +
                                        (size_t)col * DD + t * 32 + quad * 8);
        }

    floatx4 acc[4][2];
#pragma unroll
    for (int i = 0; i < 4; ++i)
#pragma unroll
        for (int j = 0; j < 2; ++j) acc[i][j] = (floatx4){0.f, 0.f, 0.f, 0.f};

    // A fragments from global: per row-stripe, batch all 8 16-B loads into
    // registers first (8 in flight), then the 16 dependent MFMAs.
#pragma unroll
    for (int i = 0; i < 4; ++i) {
        int row = bm + i * 16 + lane15;
        row = row < NN ? row : 0;
        const u16* pa = xs + ((size_t)kw * NN + row) * DD + quad * 8;
        short8 a[8];
#pragma unroll
        for (int t = 0; t < 8; ++t) a[t] = *(const short8*)(pa + t * 32);
#pragma unroll
        for (int t = 0; t < 8; ++t) {
            acc[i][0] = __builtin_amdgcn_mfma_f32_16x16x32_bf16(a[t], bf[t][0], acc[i][0], 0, 0, 0);
            acc[i][1] = __builtin_amdgcn_mfma_f32_16x16x32_bf16(a[t], bf[t][1], acc[i][1], 0, 0, 0);
        }
    }

    // sim: per row sum over this wave's 32 cols of tanh(v+batt)*q
#pragma unroll
    for (int i = 0; i < 4; ++i) {
#pragma unroll
        for (int r = 0; r < 4; ++r) {
            float p = 0.f;
#pragma unroll
            for (int j = 0; j < 2; ++j) {
                int col = ch * 32 + j * 16 + lane15;
                float v = acc[i][j][r] + batt[kw * ATTD + col];
                float ex = __expf(2.f * v);
                float th = 1.f - 2.f / (ex + 1.f);     // tanh, inf-safe
                p += th * qv[kw * ATTD + col];
            }
            p += __shfl_xor(p, 1, 64);
            p += __shfl_xor(p, 2, 64);
            p += __shfl_xor(p, 4, 64);
            p += __shfl_xor(p, 8, 64);
            if (lane15 == 0) simbuf[kw][ch][i * 16 + quad * 4 + r] = p;
        }
    }
    __syncthreads();

    // combine: 64 rows x 32 16B-chunks / 256 threads = 8 items; xs from global (coalesced)
#pragma unroll 4
    for (int it = 0; it < 8; ++it) {
        int item = tid + it * 256;
        int row = item >> 5, c8 = item & 31;
        int grow = bm + row;
        if (grow >= NN) continue;
        float s0 = simbuf[0][0][row] + simbuf[0][1][row];
        float s1 = simbuf[1][0][row] + simbuf[1][1][row];
        float m = fmaxf(s0, s1);
        float e0 = __expf(s0 - m), e1 = __expf(s1 - m);
        float inv = 1.f / (e0 + e1);
        float a0 = e0 * inv, a1 = e1 * inv;
        uint4 x0 = *(const uint4*)(xs + (size_t)grow * DD + c8 * 8);
        uint4 x1 = *(const uint4*)(xs + ((size_t)NN + grow) * DD + c8 * 8);
        const float* bp = gcnb + c8 * 8;
        uint4 hiw, low;
        u16* hp = (u16*)&hiw; u16* lp = (u16*)&low;
        const u32* xp0 = (const u32*)&x0; const u32* xp1 = (const u32*)&x1;
#pragma unroll
        for (int j = 0; j < 4; ++j) {
            float2 f0 = __bfloat1622float2(*(const __hip_bfloat162*)&xp0[j]);
            float2 f1 = __bfloat1622float2(*(const __hip_bfloat162*)&xp1[j]);
            float ra = fmaxf(0.f, a0 * f0.x + a1 * f1.x + bp[2 * j]);
            float rb = fmaxf(0.f, a0 * f0.y + a1 * f1.y + bp[2 * j + 1]);
            u16 ha = f2bf(ra), hb = f2bf(rb);
            hp[2 * j] = ha; hp[2 * j + 1] = hb;
            lp[2 * j] = f2bf(ra - bf2f(ha));
            lp[2 * j + 1] = f2bf(rb - bf2f(hb));
        }
        *(uint4*)(h_hi + (size_t)grow * DD + c8 * 8) = hiw;
        *(uint4*)(h_lo + (size_t)grow * DD + c8 * 8) = low;
    }
}

extern "C" void kernel_launch(void* const* d_in, const int* in_sizes, int n_in,
                              void* d_out, int out_size, void* d_ws, size_t ws_size,
                              hipStream_t stream) {
    const float* x     = (const float*)d_in[0];
    const int*   ei    = (const int*)d_in[1];
    const float* ew    = (const float*)d_in[2];
    const float* gamma = (const float*)d_in[3];
    const float* beta  = (const float*)d_in[4];
    const float* gcn_W = (const float*)d_in[5];
    const float* gcn_b = (const float*)d_in[6];
    const float* att_W = (const float*)d_in[7];
    const float* att_b = (const float*)d_in[8];
    const float* att_q = (const float*)d_in[9];
    const float* pW1   = (const float*)d_in[10];
    const float* pb1   = (const float*)d_in[11];
    const float* pW2   = (const float*)d_in[12];
    const float* pb2   = (const float*)d_in[13];
    float* out = (float*)d_out;

    char* wsb = (char*)d_ws;
    size_t off = 0;
    auto alloc = [&](size_t bytes) -> void* {
        void* p = wsb + off;
        off += (bytes + 255) & ~(size_t)255;
        return p;
    };
    u16*   xs    = (u16*)alloc((size_t)KD * NN * DD * 2);     // 102.4 MB (bf16)
    u16*   h_hi  = (u16*)alloc((size_t)NN * DD * 2);          // 51.2 MB
    u16*   h_lo  = (u16*)alloc((size_t)NN * DD * 2);          // 51.2 MB
    u16*   xw    = (u16*)alloc((size_t)NN * DD * 2);          // 51.2 MB
    float* p1tmp = (float*)xw;                                // N*H1*4, exact reuse
    float* dinv  = (float*)alloc((size_t)KN * 4);             // adjacent to starts
    int*   starts= (int*)alloc(((size_t)KN + 1) * 4);
    int2*  edata = (int2*)alloc((size_t)KD * EE * 8);         // 6.4 MB
    float* bnsums= (float*)alloc(2 * DD * 4);
    u16*   gcnWb = (u16*)alloc((size_t)LL * DD * DD * 2);
    u16*   attWb = (u16*)alloc((size_t)LL * KD * ATTD * DD * 2);
    u16*   pW1b  = (u16*)alloc((size_t)HH1 * DD * 2);
    u16*   pW2b  = (u16*)alloc((size_t)HH2 * HH1 * 2);
    float* batt  = (float*)alloc((size_t)LL * KD * ATTD * 4);
    int*   bsums = (int*)alloc((size_t)SCAN_NB * 4);

    // ---- setup: all weight converts in ONE kernel + att bias fold ----
    wconv_all<<<(WC_TOTAL + 255) / 256, 256, 0, stream>>>(
        gcn_W, gcnWb, att_W, attWb, pW1, pW1b, pW2, pW2b);
    att_bias_fold<<<LL * KD, ATTD, 0, stream>>>(att_W, att_b, gcn_b, batt);

    // ---- BatchNorm -> h (pre-split) ----
    hipMemsetAsync(bnsums, 0, 2 * DD * 4, stream);
    bn_stats<<<800, 256, 0, stream>>>(x, bnsums);
    bn_apply<<<25000, 256, 0, stream>>>(x, bnsums, gamma, beta, h_hi, h_lo);

    // ---- degree / CSR (layer-invariant); dinv+starts zeroed in one memset ----
    hipMemsetAsync(dinv, 0, (size_t)KN * 4 + ((size_t)KN + 1) * 4, stream);
    deg_count<<<(KD * EE + 255) / 256, 256, 0, stream>>>(ei, ew, dinv, starts);
    dinv_kernel<<<(KN + 255) / 256, 256, 0, stream>>>(dinv);
    scan_blocks<<<SCAN_NB, 256, 0, stream>>>(starts, bsums);
    scan_sums<<<1, 1024, 0, stream>>>(bsums);
    scan_add<<<SCAN_NB, 256, 0, stream>>>(starts, bsums);
    csr_fill<<<(KD * EE + 255) / 256, 256, 0, stream>>>(ei, ew, dinv, starts, edata);

    const int MB64 = (NN + 63) / 64;     // 1563
    for (int l = 0; l < LL; ++l) {
        // xw(bf16) = h @ gcn_W[l] — BM=64 x BN=256, copy-only staging
        gemm_mfma<256, 1, true, false, 0><<<dim3(MB64, 1), 256, 0, stream>>>(
            nullptr, h_hi, h_lo, gcnWb + (size_t)l * DD * DD, nullptr,
            nullptr, xw, NN, DD, DD);
        gather_agg<<<(KN + 7) / 8, 256, 0, stream>>>(starts, edata, xw, xs);
        att_combine<<<MB64, 256, 0, stream>>>(
            xs, attWb + (size_t)l * KD * ATTD * DD,
            batt + (size_t)l * KD * ATTD, att_q + (size_t)l * KD * ATTD,
            gcn_b + l * DD, h_hi, h_lo);
    }

    // ---- projection head ----
    gemm_mfma<128, 0, true, true, 1><<<dim3(MB64, 1), 256, 0, stream>>>(
        nullptr, h_hi, h_lo, pW1b, pb1, p1tmp, nullptr, NN, DD, HH1);
    gemm_mfma<64, 0, false, true, 1><<<dim3(MB64, 1), 256, 0, stream>>>(
        p1tmp, nullptr, nullptr, pW2b, pb2, out, nullptr, NN, HH1, HH2);
}

// Round 8
// 967.921 us; speedup vs baseline: 1.0275x; 1.0250x over previous
//
#include <hip/hip_runtime.h>
#include <hip/hip_bf16.h>
#include <math.h>

#define NN 100000
#define EE 400000
#define KD 2
#define DD 256
#define ATTD 64
#define LL 3
#define HH1 128
#define HH2 64
#define EPSV 1e-5f
#define SLOPE 0.01f
#define KN (KD * NN)

typedef short short8 __attribute__((ext_vector_type(8)));
typedef float floatx4 __attribute__((ext_vector_type(4)));
typedef unsigned int u32x4 __attribute__((ext_vector_type(4)));
typedef unsigned short u16;
typedef unsigned int u32;
typedef unsigned long long u64;

__device__ __forceinline__ u16 f2bf(float f) {
    u32 u = __float_as_uint(f);
    return (u16)((u + 0x7fffu + ((u >> 16) & 1u)) >> 16);
}
__device__ __forceinline__ float bf2f(u16 h) {
    return __uint_as_float((u32)h << 16);
}

// ---------------- BatchNorm ----------------
__global__ void bn_stats(const float* __restrict__ x, float* __restrict__ sums) {
    int d = threadIdx.x;
    int r0 = blockIdx.x * 125;
    float s = 0.f, sq = 0.f;
    for (int r = r0; r < r0 + 125; ++r) {
        float v = x[(size_t)r * DD + d];
        s += v; sq += v * v;
    }
    atomicAdd(&sums[d], s);
    atomicAdd(&sums[DD + d], sq);
}

// writes h as pre-split bf16 hi/lo planes
__global__ void bn_apply(const float* __restrict__ x, const float* __restrict__ sums,
                         const float* __restrict__ gamma, const float* __restrict__ beta,
                         u16* __restrict__ h_hi, u16* __restrict__ h_lo) {
    size_t i = (size_t)blockIdx.x * blockDim.x + threadIdx.x;
    const float inv_n = 1.f / NN;
    int dq = (int)(i & 63) * 4;
    float4 xv = ((const float4*)x)[i];
    ushort4 hv, lv;
    float* xp = (float*)&xv;
    u16* hp = (u16*)&hv; u16* lp = (u16*)&lv;
#pragma unroll
    for (int j = 0; j < 4; ++j) {
        int d = dq + j;
        float mu = sums[d] * inv_n;
        float var = sums[DD + d] * inv_n - mu * mu;
        float inv = rsqrtf(var + EPSV);
        float v = (xp[j] - mu) * inv * gamma[d] + beta[d];
        u16 hb = f2bf(v);
        hp[j] = hb;
        lp[j] = f2bf(v - bf2f(hb));
    }
    ((ushort4*)h_hi)[i] = hv;
    ((ushort4*)h_lo)[i] = lv;
}

// ---------------- degree + CSR count (merged) ----------------
__global__ void deg_count(const int* __restrict__ ei, const float* __restrict__ w,
                          float* __restrict__ deg, int* __restrict__ counts) {
    int i = blockIdx.x * blockDim.x + threadIdx.x;
    if (i >= KD * EE) return;
    int k = i / EE, e = i - k * EE;
    int col = ei[(size_t)k * 2 * EE + EE + e];
    atomicAdd(&deg[k * NN + col], w[i]);
    atomicAdd(&counts[k * NN + col], 1);
}

__global__ void dinv_kernel(float* __restrict__ d) {
    int i = blockIdx.x * blockDim.x + threadIdx.x;
    if (i >= KD * NN) return;
    float v = d[i];
    d[i] = v > 0.f ? 1.f / sqrtf(v) : 0.f;
}

#define SCAN_NB ((KN + 255) / 256)   // 782
__global__ void scan_blocks(int* __restrict__ starts, int* __restrict__ bsums) {
    __shared__ int tmp[256];
    int t = threadIdx.x;
    int idx = blockIdx.x * 256 + t;
    int v = (idx < KN) ? starts[idx] : 0;
    tmp[t] = v;
    __syncthreads();
#pragma unroll
    for (int off = 1; off < 256; off <<= 1) {
        int s = (t >= off) ? tmp[t - off] : 0;
        __syncthreads();
        tmp[t] += s;
        __syncthreads();
    }
    if (idx < KN) starts[idx] = tmp[t] - v;          // exclusive
    if (t == 255) bsums[blockIdx.x] = tmp[255];      // block total
}

__global__ void scan_sums(int* __restrict__ bsums) {
    __shared__ int tmp[1024];
    int t = threadIdx.x;
    int v = (t < SCAN_NB) ? bsums[t] : 0;
    tmp[t] = v;
    __syncthreads();
#pragma unroll
    for (int off = 1; off < 1024; off <<= 1) {
        int s = (t >= off) ? tmp[t - off] : 0;
        __syncthreads();
        tmp[t] += s;
        __syncthreads();
    }
    if (t < SCAN_NB) bsums[t] = tmp[t] - v;          // exclusive
}

__global__ void scan_add(int* __restrict__ starts, const int* __restrict__ bsums) {
    int idx = blockIdx.x * 256 + threadIdx.x;
    if (idx < KN) starts[idx] += bsums[blockIdx.x];
}

__global__ void csr_fill(const int* __restrict__ ei, const float* __restrict__ w,
                         const float* __restrict__ dinv,
                         int* __restrict__ starts, int2* __restrict__ edata) {
    int i = blockIdx.x * blockDim.x + threadIdx.x;
    if (i >= KD * EE) return;
    int k = i / EE, e = i - k * EE;
    const int* eik = ei + (size_t)k * 2 * EE;
    int row = eik[e], col = eik[EE + e];
    float nv = dinv[k * NN + col] * w[i] * dinv[k * NN + row];
    int pos = atomicAdd(&starts[k * NN + col], 1);
    edata[pos] = make_int2(row, __float_as_int(nv));
}

// ---------------- gather aggregation v2: 2 nodes per wave (32-lane halves) ----------------
// Doubles memory-level parallelism per wave: two independent gather chains,
// 16 B/lane (uint4) keeps each row read a fully-coalesced 512 B segment.
// Plain (cached) store: xs (102 MB) stays L3-resident (256 MB) so att_combine's
// staging reads hit L3 instead of HBM. Verify via att_combine FETCH_SIZE.
__device__ __forceinline__ void fma_row8(float4& a0, float4& a1, uint4 w, float nv) {
    float2 f0 = __bfloat1622float2(*(const __hip_bfloat162*)&w.x);
    float2 f1 = __bfloat1622float2(*(const __hip_bfloat162*)&w.y);
    float2 f2 = __bfloat1622float2(*(const __hip_bfloat162*)&w.z);
    float2 f3 = __bfloat1622float2(*(const __hip_bfloat162*)&w.w);
    a0.x += nv * f0.x; a0.y += nv * f0.y; a0.z += nv * f1.x; a0.w += nv * f1.y;
    a1.x += nv * f2.x; a1.y += nv * f2.y; a1.z += nv * f3.x; a1.w += nv * f3.y;
}

__global__ __launch_bounds__(256) void gather_agg(
        const int* __restrict__ starts, const int2* __restrict__ edata,
        const u16* __restrict__ xw, u16* __restrict__ xs) {
    int wv = blockIdx.x * 4 + (threadIdx.x >> 6);
    int lane = threadIdx.x & 63;
    int half = lane >> 5, l32 = lane & 31;
    int widx = wv * 2 + half;            // KN = 200000 is exact for 25000 blocks
    if (widx >= KN) return;
    int begin = widx ? starts[widx - 1] : 0;
    int end = starts[widx];
    int deg = end - begin;
    float4 acc0 = make_float4(0.f, 0.f, 0.f, 0.f);
    float4 acc1 = make_float4(0.f, 0.f, 0.f, 0.f);

    // per-half prefetch of up to 32 edge records (deg>32 ~ never for Poisson(4))
    int2 ed = (l32 < deg) ? edata[begin + l32] : make_int2(0, 0);
    int dmain = deg > 32 ? 32 : deg;
    int base = half << 5;                // shuffle sources stay within own half

    int j = 0;
    for (; j + 4 <= dmain; j += 4) {
        int r0 = __shfl(ed.x, base + j),     r1 = __shfl(ed.x, base + j + 1);
        int r2 = __shfl(ed.x, base + j + 2), r3 = __shfl(ed.x, base + j + 3);
        float n0 = __int_as_float(__shfl(ed.y, base + j));
        float n1 = __int_as_float(__shfl(ed.y, base + j + 1));
        float n2 = __int_as_float(__shfl(ed.y, base + j + 2));
        float n3 = __int_as_float(__shfl(ed.y, base + j + 3));
        uint4 w0 = *(const uint4*)(xw + (size_t)r0 * DD + l32 * 8);
        uint4 w1 = *(const uint4*)(xw + (size_t)r1 * DD + l32 * 8);
        uint4 w2 = *(const uint4*)(xw + (size_t)r2 * DD + l32 * 8);
        uint4 w3 = *(const uint4*)(xw + (size_t)r3 * DD + l32 * 8);
        fma_row8(acc0, acc1, w0, n0);
        fma_row8(acc0, acc1, w1, n1);
        fma_row8(acc0, acc1, w2, n2);
        fma_row8(acc0, acc1, w3, n3);
    }
    for (; j < dmain; ++j) {
        int r = __shfl(ed.x, base + j);
        float nv = __int_as_float(__shfl(ed.y, base + j));
        uint4 w = *(const uint4*)(xw + (size_t)r * DD + l32 * 8);
        fma_row8(acc0, acc1, w, nv);
    }
    for (int e = begin + 32; e < end; ++e) {     // rare fallback: deg > 32
        int2 ee = edata[e];
        float nv = __int_as_float(ee.y);
        uint4 w = *(const uint4*)(xw + (size_t)ee.x * DD + l32 * 8);
        fma_row8(acc0, acc1, w, nv);
    }

    u32x4 st;
    st.x = (u32)f2bf(acc0.x) | ((u32)f2bf(acc0.y) << 16);
    st.y = (u32)f2bf(acc0.z) | ((u32)f2bf(acc0.w) << 16);
    st.z = (u32)f2bf(acc1.x) | ((u32)f2bf(acc1.y) << 16);
    st.w = (u32)f2bf(acc1.z) | ((u32)f2bf(acc1.w) << 16);
    *(u32x4*)(xs + (size_t)widx * DD + l32 * 8) = st;
}

// ---------------- merged weight convert+transpose for ALL weights ----------------
#define GCN_T (LL * DD * DD)                 // 196608
#define ATT_T (LL * KD * DD * ATTD)          // 98304
#define P1_T  (DD * HH1)                     // 32768
#define P2_T  (HH1 * HH2)                    // 8192
#define WC_TOTAL (GCN_T + ATT_T + P1_T + P2_T)
__device__ __forceinline__ void wconv1(const float* __restrict__ W, u16* __restrict__ Wt,
                                       int i, int Kd, int Nc) {
    int kk = i / Nc, n = i - kk * Nc;
    Wt[(size_t)n * Kd + kk] = f2bf(W[i]);
}
__global__ void wconv_all(const float* __restrict__ gcnW, u16* __restrict__ gcnWb,
                          const float* __restrict__ attW, u16* __restrict__ attWb,
                          const float* __restrict__ pW1, u16* __restrict__ pW1b,
                          const float* __restrict__ pW2, u16* __restrict__ pW2b) {
    int gid = blockIdx.x * 256 + threadIdx.x;
    if (gid >= WC_TOTAL) return;
    if (gid < GCN_T) {
        int l = gid >> 16, i = gid & 65535;
        wconv1(gcnW + (size_t)l * DD * DD, gcnWb + (size_t)l * DD * DD, i, DD, DD);
    } else if (gid < GCN_T + ATT_T) {
        int g = gid - GCN_T;
        int lk = g >> 14, i = g & 16383;
        wconv1(attW + (size_t)lk * DD * ATTD, attWb + (size_t)lk * ATTD * DD, i, DD, ATTD);
    } else if (gid < GCN_T + ATT_T + P1_T) {
        wconv1(pW1, pW1b, gid - (GCN_T + ATT_T), DD, HH1);
    } else {
        wconv1(pW2, pW2b, gid - (GCN_T + ATT_T + P1_T), HH1, HH2);
    }
}

// ---------------- fold gcn_b into attention bias ----------------
__global__ void att_bias_fold(const float* __restrict__ attW, const float* __restrict__ attb,
                              const float* __restrict__ gcnb, float* __restrict__ batt) {
    int lk = blockIdx.x;          // 0..5
    int a = threadIdx.x;          // 0..63
    int l = lk >> 1;
    const float* W = attW + (size_t)lk * DD * ATTD;
    const float* gb = gcnb + l * DD;
    float s = attb[lk * ATTD + a];
    for (int d = 0; d < DD; ++d) s += gb[d] * W[d * ATTD + a];
    batt[lk * ATTD + a] = s;
}

#define LDSP 40   // LDS row stride in u16 (32 + 8 pad)

// ---------------- MFMA GEMM, BM=64, 4 waves laid out 1x4 across columns ----------------
template<int BN_, int MODE, bool PRESPLIT, bool BIAS, int ACT>
__global__ __launch_bounds__(256) void gemm_mfma(
        const float* __restrict__ A,
        const u16* __restrict__ Ahi, const u16* __restrict__ Alo,
        const u16* __restrict__ Bt, const float* __restrict__ bias,
        float* __restrict__ Cf, u16* __restrict__ Cb,
        int M, int Kd, int Nc) {
    constexpr int JW = BN_ / 64;           // j-frags per wave (wave covers BN_/4 cols)
    __shared__ u16 AsHi[64 * LDSP];
    __shared__ u16 AsLo[64 * LDSP];
    __shared__ u16 Bs[BN_ * LDSP];

    const int tid = threadIdx.x;
    const int lane = tid & 63, wx = tid >> 6;      // wave id 0..3 across columns
    const int lane15 = lane & 15, quad = lane >> 4;
    const int bm = blockIdx.x * 64;
    const int bn = blockIdx.y * BN_;

    floatx4 acc[4][JW];
#pragma unroll
    for (int i = 0; i < 4; ++i)
#pragma unroll
        for (int j = 0; j < JW; ++j) acc[i][j] = (floatx4){0.f, 0.f, 0.f, 0.f};

    for (int k0 = 0; k0 < Kd; k0 += 32) {
        if constexpr (PRESPLIT) {
            {   // 64 rows x 32 u16 per plane = 256 uint4 each; 1 per thread
                int m = tid >> 2, ko = (tid & 3) << 3;
                uint4 vh = make_uint4(0, 0, 0, 0), vl = make_uint4(0, 0, 0, 0);
                if (bm + m < M) {
                    vh = *(const uint4*)(Ahi + (size_t)(bm + m) * Kd + k0 + ko);
                    vl = *(const uint4*)(Alo + (size_t)(bm + m) * Kd + k0 + ko);
                }
                *(uint4*)(void*)(AsHi + m * LDSP + ko) = vh;
                *(uint4*)(void*)(AsLo + m * LDSP + ko) = vl;
            }
        } else {
#pragma unroll
            for (int t = tid; t < 512; t += 256) {
                int m = t >> 3, k4 = (t & 7) << 2;
                float4 v = make_float4(0.f, 0.f, 0.f, 0.f);
                if (bm + m < M) v = *(const float4*)(A + (size_t)(bm + m) * Kd + k0 + k4);
                u16 h0 = f2bf(v.x), h1 = f2bf(v.y), h2 = f2bf(v.z), h3 = f2bf(v.w);
                *(ushort4*)(void*)(AsHi + m * LDSP + k4) = make_ushort4(h0, h1, h2, h3);
                u16 l0 = f2bf(v.x - bf2f(h0)), l1 = f2bf(v.y - bf2f(h1));
                u16 l2 = f2bf(v.z - bf2f(h2)), l3 = f2bf(v.w - bf2f(h3));
                *(ushort4*)(void*)(AsLo + m * LDSP + k4) = make_ushort4(l0, l1, l2, l3);
            }
        }
#pragma unroll
        for (int t = tid; t < BN_ * 4; t += 256) {
            int n = t >> 2, ko = (t & 3) << 3;
            uint4 w = *(const uint4*)(Bt + (size_t)(bn + n) * Kd + k0 + ko);
            *(uint4*)(void*)(Bs + n * LDSP + ko) = w;
        }
        __syncthreads();

        const u16* pA  = AsHi + lane15 * LDSP + quad * 8;
        const u16* pAl = AsLo + lane15 * LDSP + quad * 8;
        const u16* pB  = Bs + (wx * (BN_ / 4) + lane15) * LDSP + quad * 8;
        short8 b[JW];
#pragma unroll
        for (int j = 0; j < JW; ++j) b[j] = *(const short8*)(pB + j * 16 * LDSP);
#pragma unroll
        for (int i = 0; i < 4; ++i) {
            short8 a = *(const short8*)(pA + i * 16 * LDSP);
#pragma unroll
            for (int j = 0; j < JW; ++j)
                acc[i][j] = __builtin_amdgcn_mfma_f32_16x16x32_bf16(a, b[j], acc[i][j], 0, 0, 0);
        }
#pragma unroll
        for (int i = 0; i < 4; ++i) {
            short8 a = *(const short8*)(pAl + i * 16 * LDSP);
#pragma unroll
            for (int j = 0; j < JW; ++j)
                acc[i][j] = __builtin_amdgcn_mfma_f32_16x16x32_bf16(a, b[j], acc[i][j], 0, 0, 0);
        }
        __syncthreads();
    }

#pragma unroll
    for (int i = 0; i < 4; ++i) {
#pragma unroll
        for (int r = 0; r < 4; ++r) {
            int row = bm + i * 16 + quad * 4 + r;
            if (row >= M) continue;
#pragma unroll
            for (int j = 0; j < JW; ++j) {
                int col = bn + wx * (BN_ / 4) + j * 16 + lane15;
                float v = acc[i][j][r];
                if constexpr (BIAS) v += bias[col];
                if constexpr (ACT == 1) v = v > 0.f ? v : SLOPE * v;
                if constexpr (MODE == 0) Cf[(size_t)row * Nc + col] = v;
                else                     Cb[(size_t)row * Nc + col] = f2bf(v);
            }
        }
    }
}

// ---------------- fused attention v6: K-tiled LDS staging (gemm_mfma pattern) ----------------
// Rounds 3-7 lesson: reading MFMA operands straight from global makes the phase
// latency-serial, and no launch-bounds/waves_per_eu knob makes the compiler hold
// a 64-VGPR B-fragment array resident (48->76 VGPR, dur flat at 75 us).
// Fix = the structure that already works in gemm_mfma: K-tile both operands
// through small LDS buffers (2k x 64 x 32 each, ~21.5 KB total), coalesced
// uint4 staging with multiple loads in flight, MFMA reads via ds_read_b128.
// No big register arrays -> ~80 VGPR -> up to 6 blocks/CU (entire grid resident).
__global__ __launch_bounds__(256) void att_combine(
        const u16* __restrict__ xs, const u16* __restrict__ Bt,
        const float* __restrict__ batt, const float* __restrict__ qv,
        const float* __restrict__ gcnb,
        u16* __restrict__ h_hi, u16* __restrict__ h_lo) {
    __shared__ u16 As[2 * 64 * LDSP];            // 10240 B: A tiles, both k
    __shared__ u16 Bs[2 * 64 * LDSP];            // 10240 B: B tiles, both k
    __shared__ float simbuf[KD][2][64];

    const int tid = threadIdx.x;
    const int lane = tid & 63, waveid = tid >> 6;
    const int kw = waveid >> 1, ch = waveid & 1;
    const int lane15 = lane & 15, quad = lane >> 4;
    const int bm = blockIdx.x * 64;

    floatx4 acc[4][2];
#pragma unroll
    for (int i = 0; i < 4; ++i)
#pragma unroll
        for (int j = 0; j < 2; ++j) acc[i][j] = (floatx4){0.f, 0.f, 0.f, 0.f};

    for (int k0 = 0; k0 < DD; k0 += 32) {
        // stage A: 2k x 64 rows x 32 u16 = 512 uint4, 2 per thread
#pragma unroll
        for (int it = 0; it < 2; ++it) {
            int t = tid + it * 256;
            int k = t >> 8, m = (t >> 2) & 63, ko = (t & 3) << 3;
            uint4 v = make_uint4(0, 0, 0, 0);
            if (bm + m < NN)
                v = *(const uint4*)(xs + ((size_t)k * NN + bm + m) * DD + k0 + ko);
            *(uint4*)(void*)(As + (k * 64 + m) * LDSP + ko) = v;
        }
        // stage B: 2k x 64 attcols x 32 u16 = 512 uint4, 2 per thread (L2-hot weights)
#pragma unroll
        for (int it = 0; it < 2; ++it) {
            int t = tid + it * 256;
            int k = t >> 8, c = (t >> 2) & 63, ko = (t & 3) << 3;
            uint4 v = *(const uint4*)(Bt + ((size_t)k * ATTD + c) * DD + k0 + ko);
            *(uint4*)(void*)(Bs + (k * 64 + c) * LDSP + ko) = v;
        }
        __syncthreads();

        const u16* pA = As + (kw * 64 + lane15) * LDSP + quad * 8;
        const u16* pB = Bs + (kw * 64 + ch * 32 + lane15) * LDSP + quad * 8;
        short8 b0 = *(const short8*)(pB);
        short8 b1 = *(const short8*)(pB + 16 * LDSP);
#pragma unroll
        for (int i = 0; i < 4; ++i) {
            short8 a = *(const short8*)(pA + i * 16 * LDSP);
            acc[i][0] = __builtin_amdgcn_mfma_f32_16x16x32_bf16(a, b0, acc[i][0], 0, 0, 0);
            acc[i][1] = __builtin_amdgcn_mfma_f32_16x16x32_bf16(a, b1, acc[i][1], 0, 0, 0);
        }
        __syncthreads();
    }

    // sim: per row sum over this wave's 32 cols of tanh(v+batt)*q
#pragma unroll
    for (int i = 0; i < 4; ++i) {
#pragma unroll
        for (int r = 0; r < 4; ++r) {
            float p = 0.f;
#pragma unroll
            for (int j = 0; j < 2; ++j) {
                int col = ch * 32 + j * 16 + lane15;
                float v = acc[i][j][r] + batt[kw * ATTD + col];
                float ex = __expf(2.f * v);
                float th = 1.f - 2.f / (ex + 1.f);     // tanh, inf-safe
                p += th * qv[kw * ATTD + col];
            }
            p += __shfl_xor(p, 1, 64);
            p += __shfl_xor(p, 2, 64);
            p += __shfl_xor(p, 4, 64);
            p += __shfl_xor(p, 8, 64);
            if (lane15 == 0) simbuf[kw][ch][i * 16 + quad * 4 + r] = p;
        }
    }
    __syncthreads();

    // combine: 64 rows x 32 16B-chunks / 256 threads = 8 items; xs from global (L2-hot)
#pragma unroll 4
    for (int it = 0; it < 8; ++it) {
        int item = tid + it * 256;
        int row = item >> 5, c8 = item & 31;
        int grow = bm + row;
        if (grow >= NN) continue;
        float s0 = simbuf[0][0][row] + simbuf[0][1][row];
        float s1 = simbuf[1][0][row] + simbuf[1][1][row];
        float m = fmaxf(s0, s1);
        float e0 = __expf(s0 - m), e1 = __expf(s1 - m);
        float inv = 1.f / (e0 + e1);
        float a0 = e0 * inv, a1 = e1 * inv;
        uint4 x0 = *(const uint4*)(xs + (size_t)grow * DD + c8 * 8);
        uint4 x1 = *(const uint4*)(xs + ((size_t)NN + grow) * DD + c8 * 8);
        const float* bp = gcnb + c8 * 8;
        uint4 hiw, low;
        u16* hp = (u16*)&hiw; u16* lp = (u16*)&low;
        const u32* xp0 = (const u32*)&x0; const u32* xp1 = (const u32*)&x1;
#pragma unroll
        for (int j = 0; j < 4; ++j) {
            float2 f0 = __bfloat1622float2(*(const __hip_bfloat162*)&xp0[j]);
            float2 f1 = __bfloat1622float2(*(const __hip_bfloat162*)&xp1[j]);
            float ra = fmaxf(0.f, a0 * f0.x + a1 * f1.x + bp[2 * j]);
            float rb = fmaxf(0.f, a0 * f0.y + a1 * f1.y + bp[2 * j + 1]);
            u16 ha = f2bf(ra), hb = f2bf(rb);
            hp[2 * j] = ha; hp[2 * j + 1] = hb;
            lp[2 * j] = f2bf(ra - bf2f(ha));
            lp[2 * j + 1] = f2bf(rb - bf2f(hb));
        }
        *(uint4*)(h_hi + (size_t)grow * DD + c8 * 8) = hiw;
        *(uint4*)(h_lo + (size_t)grow * DD + c8 * 8) = low;
    }
}

extern "C" void kernel_launch(void* const* d_in, const int* in_sizes, int n_in,
                              void* d_out, int out_size, void* d_ws, size_t ws_size,
                              hipStream_t stream) {
    const float* x     = (const float*)d_in[0];
    const int*   ei    = (const int*)d_in[1];
    const float* ew    = (const float*)d_in[2];
    const float* gamma = (const float*)d_in[3];
    const float* beta  = (const float*)d_in[4];
    const float* gcn_W = (const float*)d_in[5];
    const float* gcn_b = (const float*)d_in[6];
    const float* att_W = (const float*)d_in[7];
    const float* att_b = (const float*)d_in[8];
    const float* att_q = (const float*)d_in[9];
    const float* pW1   = (const float*)d_in[10];
    const float* pb1   = (const float*)d_in[11];
    const float* pW2   = (const float*)d_in[12];
    const float* pb2   = (const float*)d_in[13];
    float* out = (float*)d_out;

    char* wsb = (char*)d_ws;
    size_t off = 0;
    auto alloc = [&](size_t bytes) -> void* {
        void* p = wsb + off;
        off += (bytes + 255) & ~(size_t)255;
        return p;
    };
    u16*   xs    = (u16*)alloc((size_t)KD * NN * DD * 2);     // 102.4 MB (bf16)
    u16*   h_hi  = (u16*)alloc((size_t)NN * DD * 2);          // 51.2 MB
    u16*   h_lo  = (u16*)alloc((size_t)NN * DD * 2);          // 51.2 MB
    u16*   xw    = (u16*)alloc((size_t)NN * DD * 2);          // 51.2 MB
    float* p1tmp = (float*)xw;                                // N*H1*4, exact reuse
    float* dinv  = (float*)alloc((size_t)KN * 4);             // adjacent to starts
    int*   starts= (int*)alloc(((size_t)KN + 1) * 4);
    int2*  edata = (int2*)alloc((size_t)KD * EE * 8);         // 6.4 MB
    float* bnsums= (float*)alloc(2 * DD * 4);
    u16*   gcnWb = (u16*)alloc((size_t)LL * DD * DD * 2);
    u16*   attWb = (u16*)alloc((size_t)LL * KD * ATTD * DD * 2);
    u16*   pW1b  = (u16*)alloc((size_t)HH1 * DD * 2);
    u16*   pW2b  = (u16*)alloc((size_t)HH2 * HH1 * 2);
    float* batt  = (float*)alloc((size_t)LL * KD * ATTD * 4);
    int*   bsums = (int*)alloc((size_t)SCAN_NB * 4);

    // ---- setup: all weight converts in ONE kernel + att bias fold ----
    wconv_all<<<(WC_TOTAL + 255) / 256, 256, 0, stream>>>(
        gcn_W, gcnWb, att_W, attWb, pW1, pW1b, pW2, pW2b);
    att_bias_fold<<<LL * KD, ATTD, 0, stream>>>(att_W, att_b, gcn_b, batt);

    // ---- BatchNorm -> h (pre-split) ----
    hipMemsetAsync(bnsums, 0, 2 * DD * 4, stream);
    bn_stats<<<800, 256, 0, stream>>>(x, bnsums);
    bn_apply<<<25000, 256, 0, stream>>>(x, bnsums, gamma, beta, h_hi, h_lo);

    // ---- degree / CSR (layer-invariant); dinv+starts zeroed in one memset ----
    hipMemsetAsync(dinv, 0, (size_t)KN * 4 + ((size_t)KN + 1) * 4, stream);
    deg_count<<<(KD * EE + 255) / 256, 256, 0, stream>>>(ei, ew, dinv, starts);
    dinv_kernel<<<(KN + 255) / 256, 256, 0, stream>>>(dinv);
    scan_blocks<<<SCAN_NB, 256, 0, stream>>>(starts, bsums);
    scan_sums<<<1, 1024, 0, stream>>>(bsums);
    scan_add<<<SCAN_NB, 256, 0, stream>>>(starts, bsums);
    csr_fill<<<(KD * EE + 255) / 256, 256, 0, stream>>>(ei, ew, dinv, starts, edata);

    const int MB64 = (NN + 63) / 64;     // 1563
    for (int l = 0; l < LL; ++l) {
        // xw(bf16) = h @ gcn_W[l] — BM=64 x BN=256, copy-only staging
        gemm_mfma<256, 1, true, false, 0><<<dim3(MB64, 1), 256, 0, stream>>>(
            nullptr, h_hi, h_lo, gcnWb + (size_t)l * DD * DD, nullptr,
            nullptr, xw, NN, DD, DD);
        gather_agg<<<(KN + 7) / 8, 256, 0, stream>>>(starts, edata, xw, xs);
        att_combine<<<MB64, 256, 0, stream>>>(
            xs, attWb + (size_t)l * KD * ATTD * DD,
            batt + (size_t)l * KD * ATTD, att_q + (size_t)l * KD * ATTD,
            gcn_b + l * DD, h_hi, h_lo);
    }

    // ---- projection head ----
    gemm_mfma<128, 0, true, true, 1><<<dim3(MB64, 1), 256, 0, stream>>>(
        nullptr, h_hi, h_lo, pW1b, pb1, p1tmp, nullptr, NN, DD, HH1);
    gemm_mfma<64, 0, false, true, 1><<<dim3(MB64, 1), 256, 0, stream>>>(
        p1tmp, nullptr, nullptr, pW2b, pb2, out, nullptr, NN, HH1, HH2);
}

// Round 9
// 929.895 us; speedup vs baseline: 1.0695x; 1.0409x over previous
//
#include <hip/hip_runtime.h>
#include <hip/hip_bf16.h>
#include <math.h>

#define NN 100000
#define EE 400000
#define KD 2
#define DD 256
#define ATTD 64
#define LL 3
#define HH1 128
#define HH2 64
#define EPSV 1e-5f
#define SLOPE 0.01f
#define KN (KD * NN)
#define WFP 33554432.0f   // 2^25 fixed-point scale for packed degree sum

typedef short short8 __attribute__((ext_vector_type(8)));
typedef float floatx4 __attribute__((ext_vector_type(4)));
typedef unsigned int u32x4 __attribute__((ext_vector_type(4)));
typedef unsigned short u16;
typedef unsigned int u32;
typedef unsigned long long u64;

__device__ __forceinline__ u16 f2bf(float f) {
    u32 u = __float_as_uint(f);
    return (u16)((u + 0x7fffu + ((u >> 16) & 1u)) >> 16);
}
__device__ __forceinline__ float bf2f(u16 h) {
    return __uint_as_float((u32)h << 16);
}

// ---------------- BatchNorm ----------------
__global__ void bn_stats(const float* __restrict__ x, float* __restrict__ sums) {
    int d = threadIdx.x;
    int r0 = blockIdx.x * 125;
    float s = 0.f, sq = 0.f;
    for (int r = r0; r < r0 + 125; ++r) {
        float v = x[(size_t)r * DD + d];
        s += v; sq += v * v;
    }
    atomicAdd(&sums[d], s);
    atomicAdd(&sums[DD + d], sq);
}

// writes h as pre-split bf16 hi/lo planes
__global__ void bn_apply(const float* __restrict__ x, const float* __restrict__ sums,
                         const float* __restrict__ gamma, const float* __restrict__ beta,
                         u16* __restrict__ h_hi, u16* __restrict__ h_lo) {
    size_t i = (size_t)blockIdx.x * blockDim.x + threadIdx.x;
    const float inv_n = 1.f / NN;
    int dq = (int)(i & 63) * 4;
    float4 xv = ((const float4*)x)[i];
    ushort4 hv, lv;
    float* xp = (float*)&xv;
    u16* hp = (u16*)&hv; u16* lp = (u16*)&lv;
#pragma unroll
    for (int j = 0; j < 4; ++j) {
        int d = dq + j;
        float mu = sums[d] * inv_n;
        float var = sums[DD + d] * inv_n - mu * mu;
        float inv = rsqrtf(var + EPSV);
        float v = (xp[j] - mu) * inv * gamma[d] + beta[d];
        u16 hb = f2bf(v);
        hp[j] = hb;
        lp[j] = f2bf(v - bf2f(hb));
    }
    ((ushort4*)h_hi)[i] = hv;
    ((ushort4*)h_lo)[i] = lv;
}

// ---------------- degree + CSR count: ONE packed u64 atomic per edge ----------------
// Round-8 PMC: deg_count was atomic-transaction-bound (WRITE_SIZE 49.9 MB =
// 1.6M atomics x 32B memory-side transactions; HBM 9%, VALU 0.5%). Packing
// count (high 32b) + fixed-point w-sum (low 32b, 2^25 scale; max node degree
// ~30 so sum < 2^30, error <= 5e-7) halves the transaction count.
__global__ void deg_count(const int* __restrict__ ei, const float* __restrict__ w,
                          u64* __restrict__ dc) {
    int i = blockIdx.x * blockDim.x + threadIdx.x;
    if (i >= KD * EE) return;
    int k = i / EE, e = i - k * EE;
    int col = ei[(size_t)k * 2 * EE + EE + e];
    u64 wfp = (u64)__float2uint_rn(w[i] * WFP);
    atomicAdd(&dc[k * NN + col], ((u64)1 << 32) | wfp);
}

// unpack: low 32b -> dinv (1/sqrt of fixed-point sum), high 32b -> starts (counts)
__global__ void dinv_pack(const u64* __restrict__ dc, float* __restrict__ dinv,
                          int* __restrict__ starts) {
    int i = blockIdx.x * blockDim.x + threadIdx.x;
    if (i >= KN) return;
    u64 p = dc[i];
    float deg = (float)(u32)p * (1.f / WFP);
    dinv[i] = deg > 0.f ? 1.f / sqrtf(deg) : 0.f;
    starts[i] = (int)(p >> 32);
}

#define SCAN_NB ((KN + 255) / 256)   // 782
__global__ void scan_blocks(int* __restrict__ starts, int* __restrict__ bsums) {
    __shared__ int tmp[256];
    int t = threadIdx.x;
    int idx = blockIdx.x * 256 + t;
    int v = (idx < KN) ? starts[idx] : 0;
    tmp[t] = v;
    __syncthreads();
#pragma unroll
    for (int off = 1; off < 256; off <<= 1) {
        int s = (t >= off) ? tmp[t - off] : 0;
        __syncthreads();
        tmp[t] += s;
        __syncthreads();
    }
    if (idx < KN) starts[idx] = tmp[t] - v;          // exclusive
    if (t == 255) bsums[blockIdx.x] = tmp[255];      // block total
}

__global__ void scan_sums(int* __restrict__ bsums) {
    __shared__ int tmp[1024];
    int t = threadIdx.x;
    int v = (t < SCAN_NB) ? bsums[t] : 0;
    tmp[t] = v;
    __syncthreads();
#pragma unroll
    for (int off = 1; off < 1024; off <<= 1) {
        int s = (t >= off) ? tmp[t - off] : 0;
        __syncthreads();
        tmp[t] += s;
        __syncthreads();
    }
    if (t < SCAN_NB) bsums[t] = tmp[t] - v;          // exclusive
}

__global__ void scan_add(int* __restrict__ starts, const int* __restrict__ bsums) {
    int idx = blockIdx.x * 256 + threadIdx.x;
    if (idx < KN) starts[idx] += bsums[blockIdx.x];
}

__global__ void csr_fill(const int* __restrict__ ei, const float* __restrict__ w,
                         const float* __restrict__ dinv,
                         int* __restrict__ starts, int2* __restrict__ edata) {
    int i = blockIdx.x * blockDim.x + threadIdx.x;
    if (i >= KD * EE) return;
    int k = i / EE, e = i - k * EE;
    const int* eik = ei + (size_t)k * 2 * EE;
    int row = eik[e], col = eik[EE + e];
    float nv = dinv[k * NN + col] * w[i] * dinv[k * NN + row];
    int pos = atomicAdd(&starts[k * NN + col], 1);
    edata[pos] = make_int2(row, __float_as_int(nv));
}

// ---------------- gather aggregation v2: 2 nodes per wave (32-lane halves) ----------------
// Doubles memory-level parallelism per wave: two independent gather chains,
// 16 B/lane (uint4) keeps each row read a fully-coalesced 512 B segment.
// Plain (cached) store: xs (102 MB) stays L3-resident (256 MB) so att_combine's
// staging reads hit L3 instead of HBM.
__device__ __forceinline__ void fma_row8(float4& a0, float4& a1, uint4 w, float nv) {
    float2 f0 = __bfloat1622float2(*(const __hip_bfloat162*)&w.x);
    float2 f1 = __bfloat1622float2(*(const __hip_bfloat162*)&w.y);
    float2 f2 = __bfloat1622float2(*(const __hip_bfloat162*)&w.z);
    float2 f3 = __bfloat1622float2(*(const __hip_bfloat162*)&w.w);
    a0.x += nv * f0.x; a0.y += nv * f0.y; a0.z += nv * f1.x; a0.w += nv * f1.y;
    a1.x += nv * f2.x; a1.y += nv * f2.y; a1.z += nv * f3.x; a1.w += nv * f3.y;
}

__global__ __launch_bounds__(256) void gather_agg(
        const int* __restrict__ starts, const int2* __restrict__ edata,
        const u16* __restrict__ xw, u16* __restrict__ xs) {
    int wv = blockIdx.x * 4 + (threadIdx.x >> 6);
    int lane = threadIdx.x & 63;
    int half = lane >> 5, l32 = lane & 31;
    int widx = wv * 2 + half;            // KN = 200000 is exact for 25000 blocks
    if (widx >= KN) return;
    int begin = widx ? starts[widx - 1] : 0;
    int end = starts[widx];
    int deg = end - begin;
    float4 acc0 = make_float4(0.f, 0.f, 0.f, 0.f);
    float4 acc1 = make_float4(0.f, 0.f, 0.f, 0.f);

    // per-half prefetch of up to 32 edge records (deg>32 ~ never for Poisson(4))
    int2 ed = (l32 < deg) ? edata[begin + l32] : make_int2(0, 0);
    int dmain = deg > 32 ? 32 : deg;
    int base = half << 5;                // shuffle sources stay within own half

    int j = 0;
    for (; j + 4 <= dmain; j += 4) {
        int r0 = __shfl(ed.x, base + j),     r1 = __shfl(ed.x, base + j + 1);
        int r2 = __shfl(ed.x, base + j + 2), r3 = __shfl(ed.x, base + j + 3);
        float n0 = __int_as_float(__shfl(ed.y, base + j));
        float n1 = __int_as_float(__shfl(ed.y, base + j + 1));
        float n2 = __int_as_float(__shfl(ed.y, base + j + 2));
        float n3 = __int_as_float(__shfl(ed.y, base + j + 3));
        uint4 w0 = *(const uint4*)(xw + (size_t)r0 * DD + l32 * 8);
        uint4 w1 = *(const uint4*)(xw + (size_t)r1 * DD + l32 * 8);
        uint4 w2 = *(const uint4*)(xw + (size_t)r2 * DD + l32 * 8);
        uint4 w3 = *(const uint4*)(xw + (size_t)r3 * DD + l32 * 8);
        fma_row8(acc0, acc1, w0, n0);
        fma_row8(acc0, acc1, w1, n1);
        fma_row8(acc0, acc1, w2, n2);
        fma_row8(acc0, acc1, w3, n3);
    }
    for (; j < dmain; ++j) {
        int r = __shfl(ed.x, base + j);
        float nv = __int_as_float(__shfl(ed.y, base + j));
        uint4 w = *(const uint4*)(xw + (size_t)r * DD + l32 * 8);
        fma_row8(acc0, acc1, w, nv);
    }
    for (int e = begin + 32; e < end; ++e) {     // rare fallback: deg > 32
        int2 ee = edata[e];
        float nv = __int_as_float(ee.y);
        uint4 w = *(const uint4*)(xw + (size_t)ee.x * DD + l32 * 8);
        fma_row8(acc0, acc1, w, nv);
    }

    u32x4 st;
    st.x = (u32)f2bf(acc0.x) | ((u32)f2bf(acc0.y) << 16);
    st.y = (u32)f2bf(acc0.z) | ((u32)f2bf(acc0.w) << 16);
    st.z = (u32)f2bf(acc1.x) | ((u32)f2bf(acc1.y) << 16);
    st.w = (u32)f2bf(acc1.z) | ((u32)f2bf(acc1.w) << 16);
    *(u32x4*)(xs + (size_t)widx * DD + l32 * 8) = st;
}

// ---------------- merged weight convert+transpose for ALL weights ----------------
#define GCN_T (LL * DD * DD)                 // 196608
#define ATT_T (LL * KD * DD * ATTD)          // 98304
#define P1_T  (DD * HH1)                     // 32768
#define P2_T  (HH1 * HH2)                    // 8192
#define WC_TOTAL (GCN_T + ATT_T + P1_T + P2_T)
__device__ __forceinline__ void wconv1(const float* __restrict__ W, u16* __restrict__ Wt,
                                       int i, int Kd, int Nc) {
    int kk = i / Nc, n = i - kk * Nc;
    Wt[(size_t)n * Kd + kk] = f2bf(W[i]);
}
__global__ void wconv_all(const float* __restrict__ gcnW, u16* __restrict__ gcnWb,
                          const float* __restrict__ attW, u16* __restrict__ attWb,
                          const float* __restrict__ pW1, u16* __restrict__ pW1b,
                          const float* __restrict__ pW2, u16* __restrict__ pW2b) {
    int gid = blockIdx.x * 256 + threadIdx.x;
    if (gid >= WC_TOTAL) return;
    if (gid < GCN_T) {
        int l = gid >> 16, i = gid & 65535;
        wconv1(gcnW + (size_t)l * DD * DD, gcnWb + (size_t)l * DD * DD, i, DD, DD);
    } else if (gid < GCN_T + ATT_T) {
        int g = gid - GCN_T;
        int lk = g >> 14, i = g & 16383;
        wconv1(attW + (size_t)lk * DD * ATTD, attWb + (size_t)lk * ATTD * DD, i, DD, ATTD);
    } else if (gid < GCN_T + ATT_T + P1_T) {
        wconv1(pW1, pW1b, gid - (GCN_T + ATT_T), DD, HH1);
    } else {
        wconv1(pW2, pW2b, gid - (GCN_T + ATT_T + P1_T), HH1, HH2);
    }
}

// ---------------- fold gcn_b into attention bias ----------------
__global__ void att_bias_fold(const float* __restrict__ attW, const float* __restrict__ attb,
                              const float* __restrict__ gcnb, float* __restrict__ batt) {
    int lk = blockIdx.x;          // 0..5
    int a = threadIdx.x;          // 0..63
    int l = lk >> 1;
    const float* W = attW + (size_t)lk * DD * ATTD;
    const float* gb = gcnb + l * DD;
    float s = attb[lk * ATTD + a];
    for (int d = 0; d < DD; ++d) s += gb[d] * W[d * ATTD + a];
    batt[lk * ATTD + a] = s;
}

#define LDSP 40   // LDS row stride in u16 (32 + 8 pad)

// ---------------- MFMA GEMM, BM=64, 4 waves laid out 1x4 across columns ----------------
template<int BN_, int MODE, bool PRESPLIT, bool BIAS, int ACT>
__global__ __launch_bounds__(256) void gemm_mfma(
        const float* __restrict__ A,
        const u16* __restrict__ Ahi, const u16* __restrict__ Alo,
        const u16* __restrict__ Bt, const float* __restrict__ bias,
        float* __restrict__ Cf, u16* __restrict__ Cb,
        int M, int Kd, int Nc) {
    constexpr int JW = BN_ / 64;           // j-frags per wave (wave covers BN_/4 cols)
    __shared__ u16 AsHi[64 * LDSP];
    __shared__ u16 AsLo[64 * LDSP];
    __shared__ u16 Bs[BN_ * LDSP];

    const int tid = threadIdx.x;
    const int lane = tid & 63, wx = tid >> 6;      // wave id 0..3 across columns
    const int lane15 = lane & 15, quad = lane >> 4;
    const int bm = blockIdx.x * 64;
    const int bn = blockIdx.y * BN_;

    floatx4 acc[4][JW];
#pragma unroll
    for (int i = 0; i < 4; ++i)
#pragma unroll
        for (int j = 0; j < JW; ++j) acc[i][j] = (floatx4){0.f, 0.f, 0.f, 0.f};

    for (int k0 = 0; k0 < Kd; k0 += 32) {
        if constexpr (PRESPLIT) {
            {   // 64 rows x 32 u16 per plane = 256 uint4 each; 1 per thread
                int m = tid >> 2, ko = (tid & 3) << 3;
                uint4 vh = make_uint4(0, 0, 0, 0), vl = make_uint4(0, 0, 0, 0);
                if (bm + m < M) {
                    vh = *(const uint4*)(Ahi + (size_t)(bm + m) * Kd + k0 + ko);
                    vl = *(const uint4*)(Alo + (size_t)(bm + m) * Kd + k0 + ko);
                }
                *(uint4*)(void*)(AsHi + m * LDSP + ko) = vh;
                *(uint4*)(void*)(AsLo + m * LDSP + ko) = vl;
            }
        } else {
#pragma unroll
            for (int t = tid; t < 512; t += 256) {
                int m = t >> 3, k4 = (t & 7) << 2;
                float4 v = make_float4(0.f, 0.f, 0.f, 0.f);
                if (bm + m < M) v = *(const float4*)(A + (size_t)(bm + m) * Kd + k0 + k4);
                u16 h0 = f2bf(v.x), h1 = f2bf(v.y), h2 = f2bf(v.z), h3 = f2bf(v.w);
                *(ushort4*)(void*)(AsHi + m * LDSP + k4) = make_ushort4(h0, h1, h2, h3);
                u16 l0 = f2bf(v.x - bf2f(h0)), l1 = f2bf(v.y - bf2f(h1));
                u16 l2 = f2bf(v.z - bf2f(h2)), l3 = f2bf(v.w - bf2f(h3));
                *(ushort4*)(void*)(AsLo + m * LDSP + k4) = make_ushort4(l0, l1, l2, l3);
            }
        }
#pragma unroll
        for (int t = tid; t < BN_ * 4; t += 256) {
            int n = t >> 2, ko = (t & 3) << 3;
            uint4 w = *(const uint4*)(Bt + (size_t)(bn + n) * Kd + k0 + ko);
            *(uint4*)(void*)(Bs + n * LDSP + ko) = w;
        }
        __syncthreads();

        const u16* pA  = AsHi + lane15 * LDSP + quad * 8;
        const u16* pAl = AsLo + lane15 * LDSP + quad * 8;
        const u16* pB  = Bs + (wx * (BN_ / 4) + lane15) * LDSP + quad * 8;
        short8 b[JW];
#pragma unroll
        for (int j = 0; j < JW; ++j) b[j] = *(const short8*)(pB + j * 16 * LDSP);
#pragma unroll
        for (int i = 0; i < 4; ++i) {
            short8 a = *(const short8*)(pA + i * 16 * LDSP);
#pragma unroll
            for (int j = 0; j < JW; ++j)
                acc[i][j] = __builtin_amdgcn_mfma_f32_16x16x32_bf16(a, b[j], acc[i][j], 0, 0, 0);
        }
#pragma unroll
        for (int i = 0; i < 4; ++i) {
            short8 a = *(const short8*)(pAl + i * 16 * LDSP);
#pragma unroll
            for (int j = 0; j < JW; ++j)
                acc[i][j] = __builtin_amdgcn_mfma_f32_16x16x32_bf16(a, b[j], acc[i][j], 0, 0, 0);
        }
        __syncthreads();
    }

#pragma unroll
    for (int i = 0; i < 4; ++i) {
#pragma unroll
        for (int r = 0; r < 4; ++r) {
            int row = bm + i * 16 + quad * 4 + r;
            if (row >= M) continue;
#pragma unroll
            for (int j = 0; j < JW; ++j) {
                int col = bn + wx * (BN_ / 4) + j * 16 + lane15;
                float v = acc[i][j][r];
                if constexpr (BIAS) v += bias[col];
                if constexpr (ACT == 1) v = v > 0.f ? v : SLOPE * v;
                if constexpr (MODE == 0) Cf[(size_t)row * Nc + col] = v;
                else                     Cb[(size_t)row * Nc + col] = f2bf(v);
            }
        }
    }
}

// ---------------- fused attention v6: K-tiled LDS staging (gemm_mfma pattern) ----------------
__global__ __launch_bounds__(256) void att_combine(
        const u16* __restrict__ xs, const u16* __restrict__ Bt,
        const float* __restrict__ batt, const float* __restrict__ qv,
        const float* __restrict__ gcnb,
        u16* __restrict__ h_hi, u16* __restrict__ h_lo) {
    __shared__ u16 As[2 * 64 * LDSP];            // 10240 B: A tiles, both k
    __shared__ u16 Bs[2 * 64 * LDSP];            // 10240 B: B tiles, both k
    __shared__ float simbuf[KD][2][64];

    const int tid = threadIdx.x;
    const int lane = tid & 63, waveid = tid >> 6;
    const int kw = waveid >> 1, ch = waveid & 1;
    const int lane15 = lane & 15, quad = lane >> 4;
    const int bm = blockIdx.x * 64;

    floatx4 acc[4][2];
#pragma unroll
    for (int i = 0; i < 4; ++i)
#pragma unroll
        for (int j = 0; j < 2; ++j) acc[i][j] = (floatx4){0.f, 0.f, 0.f, 0.f};

    for (int k0 = 0; k0 < DD; k0 += 32) {
        // stage A: 2k x 64 rows x 32 u16 = 512 uint4, 2 per thread
#pragma unroll
        for (int it = 0; it < 2; ++it) {
            int t = tid + it * 256;
            int k = t >> 8, m = (t >> 2) & 63, ko = (t & 3) << 3;
            uint4 v = make_uint4(0, 0, 0, 0);
            if (bm + m < NN)
                v = *(const uint4*)(xs + ((size_t)k * NN + bm + m) * DD + k0 + ko);
            *(uint4*)(void*)(As + (k * 64 + m) * LDSP + ko) = v;
        }
        // stage B: 2k x 64 attcols x 32 u16 = 512 uint4, 2 per thread (L2-hot weights)
#pragma unroll
        for (int it = 0; it < 2; ++it) {
            int t = tid + it * 256;
            int k = t >> 8, c = (t >> 2) & 63, ko = (t & 3) << 3;
            uint4 v = *(const uint4*)(Bt + ((size_t)k * ATTD + c) * DD + k0 + ko);
            *(uint4*)(void*)(Bs + (k * 64 + c) * LDSP + ko) = v;
        }
        __syncthreads();

        const u16* pA = As + (kw * 64 + lane15) * LDSP + quad * 8;
        const u16* pB = Bs + (kw * 64 + ch * 32 + lane15) * LDSP + quad * 8;
        short8 b0 = *(const short8*)(pB);
        short8 b1 = *(const short8*)(pB + 16 * LDSP);
#pragma unroll
        for (int i = 0; i < 4; ++i) {
            short8 a = *(const short8*)(pA + i * 16 * LDSP);
            acc[i][0] = __builtin_amdgcn_mfma_f32_16x16x32_bf16(a, b0, acc[i][0], 0, 0, 0);
            acc[i][1] = __builtin_amdgcn_mfma_f32_16x16x32_bf16(a, b1, acc[i][1], 0, 0, 0);
        }
        __syncthreads();
    }

    // sim: per row sum over this wave's 32 cols of tanh(v+batt)*q
#pragma unroll
    for (int i = 0; i < 4; ++i) {
#pragma unroll
        for (int r = 0; r < 4; ++r) {
            float p = 0.f;
#pragma unroll
            for (int j = 0; j < 2; ++j) {
                int col = ch * 32 + j * 16 + lane15;
                float v = acc[i][j][r] + batt[kw * ATTD + col];
                float ex = __expf(2.f * v);
                float th = 1.f - 2.f / (ex + 1.f);     // tanh, inf-safe
                p += th * qv[kw * ATTD + col];
            }
            p += __shfl_xor(p, 1, 64);
            p += __shfl_xor(p, 2, 64);
            p += __shfl_xor(p, 4, 64);
            p += __shfl_xor(p, 8, 64);
            if (lane15 == 0) simbuf[kw][ch][i * 16 + quad * 4 + r] = p;
        }
    }
    __syncthreads();

    // combine: 64 rows x 32 16B-chunks / 256 threads = 8 items; xs from global (L2-hot)
#pragma unroll 4
    for (int it = 0; it < 8; ++it) {
        int item = tid + it * 256;
        int row = item >> 5, c8 = item & 31;
        int grow = bm + row;
        if (grow >= NN) continue;
        float s0 = simbuf[0][0][row] + simbuf[0][1][row];
        float s1 = simbuf[1][0][row] + simbuf[1][1][row];
        float m = fmaxf(s0, s1);
        float e0 = __expf(s0 - m), e1 = __expf(s1 - m);
        float inv = 1.f / (e0 + e1);
        float a0 = e0 * inv, a1 = e1 * inv;
        uint4 x0 = *(const uint4*)(xs + (size_t)grow * DD + c8 * 8);
        uint4 x1 = *(const uint4*)(xs + ((size_t)NN + grow) * DD + c8 * 8);
        const float* bp = gcnb + c8 * 8;
        uint4 hiw, low;
        u16* hp = (u16*)&hiw; u16* lp = (u16*)&low;
        const u32* xp0 = (const u32*)&x0; const u32* xp1 = (const u32*)&x1;
#pragma unroll
        for (int j = 0; j < 4; ++j) {
            float2 f0 = __bfloat1622float2(*(const __hip_bfloat162*)&xp0[j]);
            float2 f1 = __bfloat1622float2(*(const __hip_bfloat162*)&xp1[j]);
            float ra = fmaxf(0.f, a0 * f0.x + a1 * f1.x + bp[2 * j]);
            float rb = fmaxf(0.f, a0 * f0.y + a1 * f1.y + bp[2 * j + 1]);
            u16 ha = f2bf(ra), hb = f2bf(rb);
            hp[2 * j] = ha; hp[2 * j + 1] = hb;
            lp[2 * j] = f2bf(ra - bf2f(ha));
            lp[2 * j + 1] = f2bf(rb - bf2f(hb));
        }
        *(uint4*)(h_hi + (size_t)grow * DD + c8 * 8) = hiw;
        *(uint4*)(h_lo + (size_t)grow * DD + c8 * 8) = low;
    }
}

extern "C" void kernel_launch(void* const* d_in, const int* in_sizes, int n_in,
                              void* d_out, int out_size, void* d_ws, size_t ws_size,
                              hipStream_t stream) {
    const float* x     = (const float*)d_in[0];
    const int*   ei    = (const int*)d_in[1];
    const float* ew    = (const float*)d_in[2];
    const float* gamma = (const float*)d_in[3];
    const float* beta  = (const float*)d_in[4];
    const float* gcn_W = (const float*)d_in[5];
    const float* gcn_b = (const float*)d_in[6];
    const float* att_W = (const float*)d_in[7];
    const float* att_b = (const float*)d_in[8];
    const float* att_q = (const float*)d_in[9];
    const float* pW1   = (const float*)d_in[10];
    const float* pb1   = (const float*)d_in[11];
    const float* pW2   = (const float*)d_in[12];
    const float* pb2   = (const float*)d_in[13];
    float* out = (float*)d_out;

    char* wsb = (char*)d_ws;
    size_t off = 0;
    auto alloc = [&](size_t bytes) -> void* {
        void* p = wsb + off;
        off += (bytes + 255) & ~(size_t)255;
        return p;
    };
    u16*   xs    = (u16*)alloc((size_t)KD * NN * DD * 2);     // 102.4 MB (bf16)
    u16*   h_hi  = (u16*)alloc((size_t)NN * DD * 2);          // 51.2 MB
    u16*   h_lo  = (u16*)alloc((size_t)NN * DD * 2);          // 51.2 MB
    u16*   xw    = (u16*)alloc((size_t)NN * DD * 2);          // 51.2 MB
    float* p1tmp = (float*)xw;                                // N*H1*4, exact reuse
    float* dinv  = (float*)alloc((size_t)KN * 4);
    int*   starts= (int*)alloc(((size_t)KN + 1) * 4);
    u64*   dc    = (u64*)alloc((size_t)KN * 8);               // packed deg+count
    int2*  edata = (int2*)alloc((size_t)KD * EE * 8);         // 6.4 MB
    float* bnsums= (float*)alloc(2 * DD * 4);
    u16*   gcnWb = (u16*)alloc((size_t)LL * DD * DD * 2);
    u16*   attWb = (u16*)alloc((size_t)LL * KD * ATTD * DD * 2);
    u16*   pW1b  = (u16*)alloc((size_t)HH1 * DD * 2);
    u16*   pW2b  = (u16*)alloc((size_t)HH2 * HH1 * 2);
    float* batt  = (float*)alloc((size_t)LL * KD * ATTD * 4);
    int*   bsums = (int*)alloc((size_t)SCAN_NB * 4);

    // ---- setup: all weight converts in ONE kernel + att bias fold ----
    wconv_all<<<(WC_TOTAL + 255) / 256, 256, 0, stream>>>(
        gcn_W, gcnWb, att_W, attWb, pW1, pW1b, pW2, pW2b);
    att_bias_fold<<<LL * KD, ATTD, 0, stream>>>(att_W, att_b, gcn_b, batt);

    // ---- BatchNorm -> h (pre-split) ----
    hipMemsetAsync(bnsums, 0, 2 * DD * 4, stream);
    bn_stats<<<800, 256, 0, stream>>>(x, bnsums);
    bn_apply<<<25000, 256, 0, stream>>>(x, bnsums, gamma, beta, h_hi, h_lo);

    // ---- degree / CSR (layer-invariant); single packed-atomic pass ----
    hipMemsetAsync(dc, 0, (size_t)KN * 8, stream);
    deg_count<<<(KD * EE + 255) / 256, 256, 0, stream>>>(ei, ew, dc);
    dinv_pack<<<(KN + 255) / 256, 256, 0, stream>>>(dc, dinv, starts);
    scan_blocks<<<SCAN_NB, 256, 0, stream>>>(starts, bsums);
    scan_sums<<<1, 1024, 0, stream>>>(bsums);
    scan_add<<<SCAN_NB, 256, 0, stream>>>(starts, bsums);
    csr_fill<<<(KD * EE + 255) / 256, 256, 0, stream>>>(ei, ew, dinv, starts, edata);

    const int MB64 = (NN + 63) / 64;     // 1563
    for (int l = 0; l < LL; ++l) {
        // xw(bf16) = h @ gcn_W[l] — BM=64 x BN=256, copy-only staging
        gemm_mfma<256, 1, true, false, 0><<<dim3(MB64, 1), 256, 0, stream>>>(
            nullptr, h_hi, h_lo, gcnWb + (size_t)l * DD * DD, nullptr,
            nullptr, xw, NN, DD, DD);
        gather_agg<<<(KN + 7) / 8, 256, 0, stream>>>(starts, edata, xw, xs);
        att_combine<<<MB64, 256, 0, stream>>>(
            xs, attWb + (size_t)l * KD * ATTD * DD,
            batt + (size_t)l * KD * ATTD, att_q + (size_t)l * KD * ATTD,
            gcn_b + l * DD, h_hi, h_lo);
    }

    // ---- projection head ----
    gemm_mfma<128, 0, true, true, 1><<<dim3(MB64, 1), 256, 0, stream>>>(
        nullptr, h_hi, h_lo, pW1b, pb1, p1tmp, nullptr, NN, DD, HH1);
    gemm_mfma<64, 0, false, true, 1><<<dim3(MB64, 1), 256, 0, stream>>>(
        p1tmp, nullptr, nullptr, pW2b, pb2, out, nullptr, NN, HH1, HH2);
}

// Round 10
// 911.785 us; speedup vs baseline: 1.0907x; 1.0199x over previous
//
#include <hip/hip_runtime.h>
#include <hip/hip_bf16.h>
#include <math.h>

#define NN 100000
#define EE 400000
#define KD 2
#define DD 256
#define ATTD 64
#define LL 3
#define HH1 128
#define HH2 64
#define EPSV 1e-5f
#define SLOPE 0.01f
#define KN (KD * NN)
#define WFP 33554432.0f   // 2^25 fixed-point scale for packed degree sum

typedef short short8 __attribute__((ext_vector_type(8)));
typedef float floatx4 __attribute__((ext_vector_type(4)));
typedef unsigned int u32x4 __attribute__((ext_vector_type(4)));
typedef unsigned short u16;
typedef unsigned int u32;
typedef unsigned long long u64;

__device__ __forceinline__ u16 f2bf(float f) {
    u32 u = __float_as_uint(f);
    return (u16)((u + 0x7fffu + ((u >> 16) & 1u)) >> 16);
}
__device__ __forceinline__ float bf2f(u16 h) {
    return __uint_as_float((u32)h << 16);
}

__device__ __forceinline__ void fma_row8_(float4& a0, float4& a1, uint4 w, float nv) {
    float2 f0 = __bfloat1622float2(*(const __hip_bfloat162*)&w.x);
    float2 f1 = __bfloat1622float2(*(const __hip_bfloat162*)&w.y);
    float2 f2 = __bfloat1622float2(*(const __hip_bfloat162*)&w.z);
    float2 f3 = __bfloat1622float2(*(const __hip_bfloat162*)&w.w);
    a0.x += nv * f0.x; a0.y += nv * f0.y; a0.z += nv * f1.x; a0.w += nv * f1.y;
    a1.x += nv * f2.x; a1.y += nv * f2.y; a1.z += nv * f3.x; a1.w += nv * f3.y;
}

// ---------------- BatchNorm ----------------
__global__ void bn_stats(const float* __restrict__ x, float* __restrict__ sums) {
    int d = threadIdx.x;
    int r0 = blockIdx.x * 125;
    float s = 0.f, sq = 0.f;
    for (int r = r0; r < r0 + 125; ++r) {
        float v = x[(size_t)r * DD + d];
        s += v; sq += v * v;
    }
    atomicAdd(&sums[d], s);
    atomicAdd(&sums[DD + d], sq);
}

// writes h as pre-split bf16 hi/lo planes
__global__ void bn_apply(const float* __restrict__ x, const float* __restrict__ sums,
                         const float* __restrict__ gamma, const float* __restrict__ beta,
                         u16* __restrict__ h_hi, u16* __restrict__ h_lo) {
    size_t i = (size_t)blockIdx.x * blockDim.x + threadIdx.x;
    const float inv_n = 1.f / NN;
    int dq = (int)(i & 63) * 4;
    float4 xv = ((const float4*)x)[i];
    ushort4 hv, lv;
    float* xp = (float*)&xv;
    u16* hp = (u16*)&hv; u16* lp = (u16*)&lv;
#pragma unroll
    for (int j = 0; j < 4; ++j) {
        int d = dq + j;
        float mu = sums[d] * inv_n;
        float var = sums[DD + d] * inv_n - mu * mu;
        float inv = rsqrtf(var + EPSV);
        float v = (xp[j] - mu) * inv * gamma[d] + beta[d];
        u16 hb = f2bf(v);
        hp[j] = hb;
        lp[j] = f2bf(v - bf2f(hb));
    }
    ((ushort4*)h_hi)[i] = hv;
    ((ushort4*)h_lo)[i] = lv;
}

// ---------------- degree + CSR count: ONE packed u64 atomic per edge ----------------
__global__ void deg_count(const int* __restrict__ ei, const float* __restrict__ w,
                          u64* __restrict__ dc) {
    int i = blockIdx.x * blockDim.x + threadIdx.x;
    if (i >= KD * EE) return;
    int k = i / EE, e = i - k * EE;
    int col = ei[(size_t)k * 2 * EE + EE + e];
    u64 wfp = (u64)__float2uint_rn(w[i] * WFP);
    atomicAdd(&dc[k * NN + col], ((u64)1 << 32) | wfp);
}

// unpack: low 32b -> dinv (1/sqrt of fixed-point sum), high 32b -> starts (counts)
__global__ void dinv_pack(const u64* __restrict__ dc, float* __restrict__ dinv,
                          int* __restrict__ starts) {
    int i = blockIdx.x * blockDim.x + threadIdx.x;
    if (i >= KN) return;
    u64 p = dc[i];
    float deg = (float)(u32)p * (1.f / WFP);
    dinv[i] = deg > 0.f ? 1.f / sqrtf(deg) : 0.f;
    starts[i] = (int)(p >> 32);
}

#define SCAN_NB ((KN + 255) / 256)   // 782
__global__ void scan_blocks(int* __restrict__ starts, int* __restrict__ bsums) {
    __shared__ int tmp[256];
    int t = threadIdx.x;
    int idx = blockIdx.x * 256 + t;
    int v = (idx < KN) ? starts[idx] : 0;
    tmp[t] = v;
    __syncthreads();
#pragma unroll
    for (int off = 1; off < 256; off <<= 1) {
        int s = (t >= off) ? tmp[t - off] : 0;
        __syncthreads();
        tmp[t] += s;
        __syncthreads();
    }
    if (idx < KN) starts[idx] = tmp[t] - v;          // exclusive
    if (t == 255) bsums[blockIdx.x] = tmp[255];      // block total
}

__global__ void scan_sums(int* __restrict__ bsums) {
    __shared__ int tmp[1024];
    int t = threadIdx.x;
    int v = (t < SCAN_NB) ? bsums[t] : 0;
    tmp[t] = v;
    __syncthreads();
#pragma unroll
    for (int off = 1; off < 1024; off <<= 1) {
        int s = (t >= off) ? tmp[t - off] : 0;
        __syncthreads();
        tmp[t] += s;
        __syncthreads();
    }
    if (t < SCAN_NB) bsums[t] = tmp[t] - v;          // exclusive
}

__global__ void scan_add(int* __restrict__ starts, const int* __restrict__ bsums) {
    int idx = blockIdx.x * 256 + threadIdx.x;
    if (idx < KN) starts[idx] += bsums[blockIdx.x];
}

__global__ void csr_fill(const int* __restrict__ ei, const float* __restrict__ w,
                         const float* __restrict__ dinv,
                         int* __restrict__ starts, int2* __restrict__ edata) {
    int i = blockIdx.x * blockDim.x + threadIdx.x;
    if (i >= KD * EE) return;
    int k = i / EE, e = i - k * EE;
    const int* eik = ei + (size_t)k * 2 * EE;
    int row = eik[e], col = eik[EE + e];
    float nv = dinv[k * NN + col] * w[i] * dinv[k * NN + row];
    int pos = atomicAdd(&starts[k * NN + col], 1);
    edata[pos] = make_int2(row, __float_as_int(nv));
}

// ---------------- merged weight convert+transpose for ALL weights ----------------
#define GCN_T (LL * DD * DD)                 // 196608
#define ATT_T (LL * KD * DD * ATTD)          // 98304
#define P1_T  (DD * HH1)                     // 32768
#define P2_T  (HH1 * HH2)                    // 8192
#define WC_TOTAL (GCN_T + ATT_T + P1_T + P2_T)
__device__ __forceinline__ void wconv1(const float* __restrict__ W, u16* __restrict__ Wt,
                                       int i, int Kd, int Nc) {
    int kk = i / Nc, n = i - kk * Nc;
    Wt[(size_t)n * Kd + kk] = f2bf(W[i]);
}
__global__ void wconv_all(const float* __restrict__ gcnW, u16* __restrict__ gcnWb,
                          const float* __restrict__ attW, u16* __restrict__ attWb,
                          const float* __restrict__ pW1, u16* __restrict__ pW1b,
                          const float* __restrict__ pW2, u16* __restrict__ pW2b) {
    int gid = blockIdx.x * 256 + threadIdx.x;
    if (gid >= WC_TOTAL) return;
    if (gid < GCN_T) {
        int l = gid >> 16, i = gid & 65535;
        wconv1(gcnW + (size_t)l * DD * DD, gcnWb + (size_t)l * DD * DD, i, DD, DD);
    } else if (gid < GCN_T + ATT_T) {
        int g = gid - GCN_T;
        int lk = g >> 14, i = g & 16383;
        wconv1(attW + (size_t)lk * DD * ATTD, attWb + (size_t)lk * ATTD * DD, i, DD, ATTD);
    } else if (gid < GCN_T + ATT_T + P1_T) {
        wconv1(pW1, pW1b, gid - (GCN_T + ATT_T), DD, HH1);
    } else {
        wconv1(pW2, pW2b, gid - (GCN_T + ATT_T + P1_T), HH1, HH2);
    }
}

// ---------------- fold gcn_b into attention bias ----------------
__global__ void att_bias_fold(const float* __restrict__ attW, const float* __restrict__ attb,
                              const float* __restrict__ gcnb, float* __restrict__ batt) {
    int lk = blockIdx.x;          // 0..5
    int a = threadIdx.x;          // 0..63
    int l = lk >> 1;
    const float* W = attW + (size_t)lk * DD * ATTD;
    const float* gb = gcnb + l * DD;
    float s = attb[lk * ATTD + a];
    for (int d = 0; d < DD; ++d) s += gb[d] * W[d * ATTD + a];
    batt[lk * ATTD + a] = s;
}

#define LDSP 40   // LDS row stride in u16 (32 + 8 pad)

// ---------------- MFMA GEMM, BM=64, 4 waves laid out 1x4 across columns ----------------
template<int BN_, int MODE, bool PRESPLIT, bool BIAS, int ACT>
__global__ __launch_bounds__(256) void gemm_mfma(
        const float* __restrict__ A,
        const u16* __restrict__ Ahi, const u16* __restrict__ Alo,
        const u16* __restrict__ Bt, const float* __restrict__ bias,
        float* __restrict__ Cf, u16* __restrict__ Cb,
        int M, int Kd, int Nc) {
    constexpr int JW = BN_ / 64;           // j-frags per wave (wave covers BN_/4 cols)
    __shared__ u16 AsHi[64 * LDSP];
    __shared__ u16 AsLo[64 * LDSP];
    __shared__ u16 Bs[BN_ * LDSP];

    const int tid = threadIdx.x;
    const int lane = tid & 63, wx = tid >> 6;      // wave id 0..3 across columns
    const int lane15 = lane & 15, quad = lane >> 4;
    const int bm = blockIdx.x * 64;
    const int bn = blockIdx.y * BN_;

    floatx4 acc[4][JW];
#pragma unroll
    for (int i = 0; i < 4; ++i)
#pragma unroll
        for (int j = 0; j < JW; ++j) acc[i][j] = (floatx4){0.f, 0.f, 0.f, 0.f};

    for (int k0 = 0; k0 < Kd; k0 += 32) {
        if constexpr (PRESPLIT) {
            {   // 64 rows x 32 u16 per plane = 256 uint4 each; 1 per thread
                int m = tid >> 2, ko = (tid & 3) << 3;
                uint4 vh = make_uint4(0, 0, 0, 0), vl = make_uint4(0, 0, 0, 0);
                if (bm + m < M) {
                    vh = *(const uint4*)(Ahi + (size_t)(bm + m) * Kd + k0 + ko);
                    vl = *(const uint4*)(Alo + (size_t)(bm + m) * Kd + k0 + ko);
                }
                *(uint4*)(void*)(AsHi + m * LDSP + ko) = vh;
                *(uint4*)(void*)(AsLo + m * LDSP + ko) = vl;
            }
        } else {
#pragma unroll
            for (int t = tid; t < 512; t += 256) {
                int m = t >> 3, k4 = (t & 7) << 2;
                float4 v = make_float4(0.f, 0.f, 0.f, 0.f);
                if (bm + m < M) v = *(const float4*)(A + (size_t)(bm + m) * Kd + k0 + k4);
                u16 h0 = f2bf(v.x), h1 = f2bf(v.y), h2 = f2bf(v.z), h3 = f2bf(v.w);
                *(ushort4*)(void*)(AsHi + m * LDSP + k4) = make_ushort4(h0, h1, h2, h3);
                u16 l0 = f2bf(v.x - bf2f(h0)), l1 = f2bf(v.y - bf2f(h1));
                u16 l2 = f2bf(v.z - bf2f(h2)), l3 = f2bf(v.w - bf2f(h3));
                *(ushort4*)(void*)(AsLo + m * LDSP + k4) = make_ushort4(l0, l1, l2, l3);
            }
        }
#pragma unroll
        for (int t = tid; t < BN_ * 4; t += 256) {
            int n = t >> 2, ko = (t & 3) << 3;
            uint4 w = *(const uint4*)(Bt + (size_t)(bn + n) * Kd + k0 + ko);
            *(uint4*)(void*)(Bs + n * LDSP + ko) = w;
        }
        __syncthreads();

        const u16* pA  = AsHi + lane15 * LDSP + quad * 8;
        const u16* pAl = AsLo + lane15 * LDSP + quad * 8;
        const u16* pB  = Bs + (wx * (BN_ / 4) + lane15) * LDSP + quad * 8;
        short8 b[JW];
#pragma unroll
        for (int j = 0; j < JW; ++j) b[j] = *(const short8*)(pB + j * 16 * LDSP);
#pragma unroll
        for (int i = 0; i < 4; ++i) {
            short8 a = *(const short8*)(pA + i * 16 * LDSP);
#pragma unroll
            for (int j = 0; j < JW; ++j)
                acc[i][j] = __builtin_amdgcn_mfma_f32_16x16x32_bf16(a, b[j], acc[i][j], 0, 0, 0);
        }
#pragma unroll
        for (int i = 0; i < 4; ++i) {
            short8 a = *(const short8*)(pAl + i * 16 * LDSP);
#pragma unroll
            for (int j = 0; j < JW; ++j)
                acc[i][j] = __builtin_amdgcn_mfma_f32_16x16x32_bf16(a, b[j], acc[i][j], 0, 0, 0);
        }
        __syncthreads();
    }

#pragma unroll
    for (int i = 0; i < 4; ++i) {
#pragma unroll
        for (int r = 0; r < 4; ++r) {
            int row = bm + i * 16 + quad * 4 + r;
            if (row >= M) continue;
#pragma unroll
            for (int j = 0; j < JW; ++j) {
                int col = bn + wx * (BN_ / 4) + j * 16 + lane15;
                float v = acc[i][j][r];
                if constexpr (BIAS) v += bias[col];
                if constexpr (ACT == 1) v = v > 0.f ? v : SLOPE * v;
                if constexpr (MODE == 0) Cf[(size_t)row * Nc + col] = v;
                else                     Cb[(size_t)row * Nc + col] = f2bf(v);
            }
        }
    }
}

// ---------------- FUSED gather + attention: xs never touches global memory ----------------
// BM=32 rows x both k per block (grid 3125, exact). Phase 1: 8 half-waves gather
// 64 node-rows straight into LDS As (starts prefetched 9-wide, all 8 edata windows
// in flight). Phase 2: round-8 MFMA with A from As, B K-tile staged. Phase 3: sim.
// Phase 4: combine reads xs values from As (LDS). Deletes 100 MB xs write +
// ~100 MB xs re-read per layer. LDS 44.5 KB -> 3 blocks/CU.
#define BMF 32
#define ALDS 264   // full-row stride in u16: 132 dwords == 4 mod 32 -> rows spread 8 bank-slots

__global__ __launch_bounds__(256) void att_fused(
        const int* __restrict__ starts, const int2* __restrict__ edata,
        const u16* __restrict__ xw, const u16* __restrict__ Bt,
        const float* __restrict__ batt, const float* __restrict__ qv,
        const float* __restrict__ gcnb,
        u16* __restrict__ h_hi, u16* __restrict__ h_lo) {
    __shared__ u16 As[KD * BMF * ALDS];          // 33792 B: gathered xs rows, both k
    __shared__ u16 Bs[2 * 64 * LDSP];            // 10240 B: B K-tiles, both k
    __shared__ float simbuf[KD][2][BMF];

    const int tid = threadIdx.x;
    const int lane = tid & 63, waveid = tid >> 6;
    const int l32 = tid & 31;
    const int hid = tid >> 5;                    // half-wave 0..7
    const int base = lane & 32;                  // shfl base of own half
    const int bm = blockIdx.x * BMF;             // NN % BMF == 0: no tail

    // ---- phase 1: gather 64 node-rows into As ----
    {
        const int kk = hid >> 2;                 // halves 0-3: k=0, 4-7: k=1
        const int r0 = (hid & 3) * 8;            // 8 rows per half
        const int widx0 = kk * NN + bm + r0;
        int sv = 0;
        if (l32 < 9) {
            int idx = widx0 - 1 + l32;
            sv = idx >= 0 ? starts[idx] : 0;     // starts[i] = end_i (post csr_fill)
        }
        // all 8 edata windows issued up-front (g compile-time: ed[] stays in VGPRs)
        int2 ed[8];
#pragma unroll
        for (int g = 0; g < 8; ++g) {
            int b = __shfl(sv, base + g), e = __shfl(sv, base + g + 1);
            ed[g] = (l32 < e - b) ? edata[b + l32] : make_int2(0, 0);
        }
#pragma unroll
        for (int g = 0; g < 8; ++g) {
            int b = __shfl(sv, base + g), e = __shfl(sv, base + g + 1);
            int deg = e - b;
            int dmain = deg > 32 ? 32 : deg;
            float4 a0 = make_float4(0.f, 0.f, 0.f, 0.f);
            float4 a1 = make_float4(0.f, 0.f, 0.f, 0.f);
            int j = 0;
            for (; j + 4 <= dmain; j += 4) {
                int s0 = __shfl(ed[g].x, base + j),     s1 = __shfl(ed[g].x, base + j + 1);
                int s2 = __shfl(ed[g].x, base + j + 2), s3 = __shfl(ed[g].x, base + j + 3);
                float n0 = __int_as_float(__shfl(ed[g].y, base + j));
                float n1 = __int_as_float(__shfl(ed[g].y, base + j + 1));
                float n2 = __int_as_float(__shfl(ed[g].y, base + j + 2));
                float n3 = __int_as_float(__shfl(ed[g].y, base + j + 3));
                uint4 w0 = *(const uint4*)(xw + (size_t)s0 * DD + l32 * 8);
                uint4 w1 = *(const uint4*)(xw + (size_t)s1 * DD + l32 * 8);
                uint4 w2 = *(const uint4*)(xw + (size_t)s2 * DD + l32 * 8);
                uint4 w3 = *(const uint4*)(xw + (size_t)s3 * DD + l32 * 8);
                fma_row8_(a0, a1, w0, n0);
                fma_row8_(a0, a1, w1, n1);
                fma_row8_(a0, a1, w2, n2);
                fma_row8_(a0, a1, w3, n3);
            }
            for (; j < dmain; ++j) {
                int s0 = __shfl(ed[g].x, base + j);
                float nv = __int_as_float(__shfl(ed[g].y, base + j));
                uint4 w = *(const uint4*)(xw + (size_t)s0 * DD + l32 * 8);
                fma_row8_(a0, a1, w, nv);
            }
            for (int e2 = b + 32; e2 < e; ++e2) {       // rare: deg > 32
                int2 ee = edata[e2];
                float nv = __int_as_float(ee.y);
                uint4 w = *(const uint4*)(xw + (size_t)ee.x * DD + l32 * 8);
                fma_row8_(a0, a1, w, nv);
            }
            u32x4 st;
            st.x = (u32)f2bf(a0.x) | ((u32)f2bf(a0.y) << 16);
            st.y = (u32)f2bf(a0.z) | ((u32)f2bf(a0.w) << 16);
            st.z = (u32)f2bf(a1.x) | ((u32)f2bf(a1.y) << 16);
            st.w = (u32)f2bf(a1.z) | ((u32)f2bf(a1.w) << 16);
            *(u32x4*)(void*)(As + (kk * BMF + r0 + g) * ALDS + l32 * 8) = st;
        }
    }
    __syncthreads();

    // ---- phase 2: MFMA, A from As, B K-tile staged ----
    const int kw = waveid >> 1, ch = waveid & 1;
    const int lane15 = lane & 15, quad = lane >> 4;
    floatx4 acc[2][2];
#pragma unroll
    for (int i = 0; i < 2; ++i)
#pragma unroll
        for (int j = 0; j < 2; ++j) acc[i][j] = (floatx4){0.f, 0.f, 0.f, 0.f};

    for (int k0 = 0; k0 < DD; k0 += 32) {
#pragma unroll
        for (int it = 0; it < 2; ++it) {         // stage B: 2k x 64c x 32 = 512 uint4
            int t = tid + it * 256;
            int k = t >> 8, c = (t >> 2) & 63, ko = (t & 3) << 3;
            uint4 v = *(const uint4*)(Bt + ((size_t)k * ATTD + c) * DD + k0 + ko);
            *(uint4*)(void*)(Bs + (k * 64 + c) * LDSP + ko) = v;
        }
        __syncthreads();
        const u16* pA = As + (kw * BMF + lane15) * ALDS + k0 + quad * 8;
        const u16* pB = Bs + (kw * 64 + ch * 32 + lane15) * LDSP + quad * 8;
        short8 b0 = *(const short8*)(pB);
        short8 b1 = *(const short8*)(pB + 16 * LDSP);
#pragma unroll
        for (int i = 0; i < 2; ++i) {
            short8 a = *(const short8*)(pA + i * 16 * ALDS);
            acc[i][0] = __builtin_amdgcn_mfma_f32_16x16x32_bf16(a, b0, acc[i][0], 0, 0, 0);
            acc[i][1] = __builtin_amdgcn_mfma_f32_16x16x32_bf16(a, b1, acc[i][1], 0, 0, 0);
        }
        __syncthreads();
    }

    // ---- phase 3: sim (tanh + q dot, 4-lane-group reduce) ----
#pragma unroll
    for (int i = 0; i < 2; ++i) {
#pragma unroll
        for (int r = 0; r < 4; ++r) {
            float p = 0.f;
#pragma unroll
            for (int j = 0; j < 2; ++j) {
                int col = ch * 32 + j * 16 + lane15;
                float v = acc[i][j][r] + batt[kw * ATTD + col];
                float ex = __expf(2.f * v);
                float th = 1.f - 2.f / (ex + 1.f);     // tanh, inf-safe
                p += th * qv[kw * ATTD + col];
            }
            p += __shfl_xor(p, 1, 64);
            p += __shfl_xor(p, 2, 64);
            p += __shfl_xor(p, 4, 64);
            p += __shfl_xor(p, 8, 64);
            if (lane15 == 0) simbuf[kw][ch][i * 16 + quad * 4 + r] = p;
        }
    }
    __syncthreads();

    // ---- phase 4: combine (softmax over k, relu, split) — xs from LDS ----
#pragma unroll
    for (int it = 0; it < 4; ++it) {
        int item = tid + it * 256;
        int row = item >> 5, c8 = item & 31;
        int grow = bm + row;
        float s0 = simbuf[0][0][row] + simbuf[0][1][row];
        float s1 = simbuf[1][0][row] + simbuf[1][1][row];
        float m = fmaxf(s0, s1);
        float e0 = __expf(s0 - m), e1 = __expf(s1 - m);
        float inv = 1.f / (e0 + e1);
        float a0 = e0 * inv, a1 = e1 * inv;
        uint4 x0 = *(const uint4*)(As + row * ALDS + c8 * 8);
        uint4 x1 = *(const uint4*)(As + (BMF + row) * ALDS + c8 * 8);
        const float* bp = gcnb + c8 * 8;
        uint4 hiw, low;
        u16* hp = (u16*)&hiw; u16* lp = (u16*)&low;
        const u32* xp0 = (const u32*)&x0; const u32* xp1 = (const u32*)&x1;
#pragma unroll
        for (int j = 0; j < 4; ++j) {
            float2 f0 = __bfloat1622float2(*(const __hip_bfloat162*)&xp0[j]);
            float2 f1 = __bfloat1622float2(*(const __hip_bfloat162*)&xp1[j]);
            float ra = fmaxf(0.f, a0 * f0.x + a1 * f1.x + bp[2 * j]);
            float rb = fmaxf(0.f, a0 * f0.y + a1 * f1.y + bp[2 * j + 1]);
            u16 ha = f2bf(ra), hb = f2bf(rb);
            hp[2 * j] = ha; hp[2 * j + 1] = hb;
            lp[2 * j] = f2bf(ra - bf2f(ha));
            lp[2 * j + 1] = f2bf(rb - bf2f(hb));
        }
        *(uint4*)(h_hi + (size_t)grow * DD + c8 * 8) = hiw;
        *(uint4*)(h_lo + (size_t)grow * DD + c8 * 8) = low;
    }
}

extern "C" void kernel_launch(void* const* d_in, const int* in_sizes, int n_in,
                              void* d_out, int out_size, void* d_ws, size_t ws_size,
                              hipStream_t stream) {
    const float* x     = (const float*)d_in[0];
    const int*   ei    = (const int*)d_in[1];
    const float* ew    = (const float*)d_in[2];
    const float* gamma = (const float*)d_in[3];
    const float* beta  = (const float*)d_in[4];
    const float* gcn_W = (const float*)d_in[5];
    const float* gcn_b = (const float*)d_in[6];
    const float* att_W = (const float*)d_in[7];
    const float* att_b = (const float*)d_in[8];
    const float* att_q = (const float*)d_in[9];
    const float* pW1   = (const float*)d_in[10];
    const float* pb1   = (const float*)d_in[11];
    const float* pW2   = (const float*)d_in[12];
    const float* pb2   = (const float*)d_in[13];
    float* out = (float*)d_out;

    char* wsb = (char*)d_ws;
    size_t off = 0;
    auto alloc = [&](size_t bytes) -> void* {
        void* p = wsb + off;
        off += (bytes + 255) & ~(size_t)255;
        return p;
    };
    u16*   h_hi  = (u16*)alloc((size_t)NN * DD * 2);          // 51.2 MB
    u16*   h_lo  = (u16*)alloc((size_t)NN * DD * 2);          // 51.2 MB
    u16*   xw    = (u16*)alloc((size_t)NN * DD * 2);          // 51.2 MB
    float* p1tmp = (float*)xw;                                // N*H1*4, exact reuse
    float* dinv  = (float*)alloc((size_t)KN * 4);
    int*   starts= (int*)alloc(((size_t)KN + 1) * 4);
    u64*   dc    = (u64*)alloc((size_t)KN * 8);               // packed deg+count
    int2*  edata = (int2*)alloc((size_t)KD * EE * 8);         // 6.4 MB
    float* bnsums= (float*)alloc(2 * DD * 4);
    u16*   gcnWb = (u16*)alloc((size_t)LL * DD * DD * 2);
    u16*   attWb = (u16*)alloc((size_t)LL * KD * ATTD * DD * 2);
    u16*   pW1b  = (u16*)alloc((size_t)HH1 * DD * 2);
    u16*   pW2b  = (u16*)alloc((size_t)HH2 * HH1 * 2);
    float* batt  = (float*)alloc((size_t)LL * KD * ATTD * 4);
    int*   bsums = (int*)alloc((size_t)SCAN_NB * 4);

    // ---- setup: all weight converts in ONE kernel + att bias fold ----
    wconv_all<<<(WC_TOTAL + 255) / 256, 256, 0, stream>>>(
        gcn_W, gcnWb, att_W, attWb, pW1, pW1b, pW2, pW2b);
    att_bias_fold<<<LL * KD, ATTD, 0, stream>>>(att_W, att_b, gcn_b, batt);

    // ---- BatchNorm -> h (pre-split) ----
    hipMemsetAsync(bnsums, 0, 2 * DD * 4, stream);
    bn_stats<<<800, 256, 0, stream>>>(x, bnsums);
    bn_apply<<<25000, 256, 0, stream>>>(x, bnsums, gamma, beta, h_hi, h_lo);

    // ---- degree / CSR (layer-invariant); single packed-atomic pass ----
    hipMemsetAsync(dc, 0, (size_t)KN * 8, stream);
    deg_count<<<(KD * EE + 255) / 256, 256, 0, stream>>>(ei, ew, dc);
    dinv_pack<<<(KN + 255) / 256, 256, 0, stream>>>(dc, dinv, starts);
    scan_blocks<<<SCAN_NB, 256, 0, stream>>>(starts, bsums);
    scan_sums<<<1, 1024, 0, stream>>>(bsums);
    scan_add<<<SCAN_NB, 256, 0, stream>>>(starts, bsums);
    csr_fill<<<(KD * EE + 255) / 256, 256, 0, stream>>>(ei, ew, dinv, starts, edata);

    const int MB64 = (NN + 63) / 64;     // 1563
    const int MBF  = NN / BMF;           // 3125 exact
    for (int l = 0; l < LL; ++l) {
        // xw(bf16) = h @ gcn_W[l] — BM=64 x BN=256, copy-only staging
        gemm_mfma<256, 1, true, false, 0><<<dim3(MB64, 1), 256, 0, stream>>>(
            nullptr, h_hi, h_lo, gcnWb + (size_t)l * DD * DD, nullptr,
            nullptr, xw, NN, DD, DD);
        att_fused<<<MBF, 256, 0, stream>>>(
            starts, edata, xw, attWb + (size_t)l * KD * ATTD * DD,
            batt + (size_t)l * KD * ATTD, att_q + (size_t)l * KD * ATTD,
            gcn_b + l * DD, h_hi, h_lo);
    }

    // ---- projection head ----
    gemm_mfma<128, 0, true, true, 1><<<dim3(MB64, 1), 256, 0, stream>>>(
        nullptr, h_hi, h_lo, pW1b, pb1, p1tmp, nullptr, NN, DD, HH1);
    gemm_mfma<64, 0, false, true, 1><<<dim3(MB64, 1), 256, 0, stream>>>(
        p1tmp, nullptr, nullptr, pW2b, pb2, out, nullptr, NN, HH1, HH2);
}

// Round 11
// 904.736 us; speedup vs baseline: 1.0992x; 1.0078x over previous
//
#include <hip/hip_runtime.h>
#include <hip/hip_bf16.h>
#include <math.h>

#define NN 100000
#define EE 400000
#define KD 2
#define DD 256
#define ATTD 64
#define LL 3
#define HH1 128
#define HH2 64
#define EPSV 1e-5f
#define SLOPE 0.01f
#define KN (KD * NN)
#define WFP 33554432.0f   // 2^25 fixed-point scale for packed degree sum

typedef short short8 __attribute__((ext_vector_type(8)));
typedef float floatx4 __attribute__((ext_vector_type(4)));
typedef unsigned int u32x4 __attribute__((ext_vector_type(4)));
typedef unsigned short u16;
typedef unsigned int u32;
typedef unsigned long long u64;

__device__ __forceinline__ u16 f2bf(float f) {
    u32 u = __float_as_uint(f);
    return (u16)((u + 0x7fffu + ((u >> 16) & 1u)) >> 16);
}
__device__ __forceinline__ float bf2f(u16 h) {
    return __uint_as_float((u32)h << 16);
}

__device__ __forceinline__ void fma_row8_(float4& a0, float4& a1, uint4 w, float nv) {
    float2 f0 = __bfloat1622float2(*(const __hip_bfloat162*)&w.x);
    float2 f1 = __bfloat1622float2(*(const __hip_bfloat162*)&w.y);
    float2 f2 = __bfloat1622float2(*(const __hip_bfloat162*)&w.z);
    float2 f3 = __bfloat1622float2(*(const __hip_bfloat162*)&w.w);
    a0.x += nv * f0.x; a0.y += nv * f0.y; a0.z += nv * f1.x; a0.w += nv * f1.y;
    a1.x += nv * f2.x; a1.y += nv * f2.y; a1.z += nv * f3.x; a1.w += nv * f3.y;
}

// ---------------- BatchNorm ----------------
__global__ void bn_stats(const float* __restrict__ x, float* __restrict__ sums) {
    int d = threadIdx.x;
    int r0 = blockIdx.x * 125;
    float s = 0.f, sq = 0.f;
    for (int r = r0; r < r0 + 125; ++r) {
        float v = x[(size_t)r * DD + d];
        s += v; sq += v * v;
    }
    atomicAdd(&sums[d], s);
    atomicAdd(&sums[DD + d], sq);
}

// writes h as pre-split bf16 hi/lo planes
__global__ void bn_apply(const float* __restrict__ x, const float* __restrict__ sums,
                         const float* __restrict__ gamma, const float* __restrict__ beta,
                         u16* __restrict__ h_hi, u16* __restrict__ h_lo) {
    size_t i = (size_t)blockIdx.x * blockDim.x + threadIdx.x;
    const float inv_n = 1.f / NN;
    int dq = (int)(i & 63) * 4;
    float4 xv = ((const float4*)x)[i];
    ushort4 hv, lv;
    float* xp = (float*)&xv;
    u16* hp = (u16*)&hv; u16* lp = (u16*)&lv;
#pragma unroll
    for (int j = 0; j < 4; ++j) {
        int d = dq + j;
        float mu = sums[d] * inv_n;
        float var = sums[DD + d] * inv_n - mu * mu;
        float inv = rsqrtf(var + EPSV);
        float v = (xp[j] - mu) * inv * gamma[d] + beta[d];
        u16 hb = f2bf(v);
        hp[j] = hb;
        lp[j] = f2bf(v - bf2f(hb));
    }
    ((ushort4*)h_hi)[i] = hv;
    ((ushort4*)h_lo)[i] = lv;
}

// ---------------- degree + CSR count: ONE packed u64 atomic per edge ----------------
__global__ void deg_count(const int* __restrict__ ei, const float* __restrict__ w,
                          u64* __restrict__ dc) {
    int i = blockIdx.x * blockDim.x + threadIdx.x;
    if (i >= KD * EE) return;
    int k = i / EE, e = i - k * EE;
    int col = ei[(size_t)k * 2 * EE + EE + e];
    u64 wfp = (u64)__float2uint_rn(w[i] * WFP);
    atomicAdd(&dc[k * NN + col], ((u64)1 << 32) | wfp);
}

// unpack: low 32b -> dinv (1/sqrt of fixed-point sum), high 32b -> starts (counts)
__global__ void dinv_pack(const u64* __restrict__ dc, float* __restrict__ dinv,
                          int* __restrict__ starts) {
    int i = blockIdx.x * blockDim.x + threadIdx.x;
    if (i >= KN) return;
    u64 p = dc[i];
    float deg = (float)(u32)p * (1.f / WFP);
    dinv[i] = deg > 0.f ? 1.f / sqrtf(deg) : 0.f;
    starts[i] = (int)(p >> 32);
}

#define SCAN_NB ((KN + 255) / 256)   // 782
__global__ void scan_blocks(int* __restrict__ starts, int* __restrict__ bsums) {
    __shared__ int tmp[256];
    int t = threadIdx.x;
    int idx = blockIdx.x * 256 + t;
    int v = (idx < KN) ? starts[idx] : 0;
    tmp[t] = v;
    __syncthreads();
#pragma unroll
    for (int off = 1; off < 256; off <<= 1) {
        int s = (t >= off) ? tmp[t - off] : 0;
        __syncthreads();
        tmp[t] += s;
        __syncthreads();
    }
    if (idx < KN) starts[idx] = tmp[t] - v;          // exclusive
    if (t == 255) bsums[blockIdx.x] = tmp[255];      // block total
}

__global__ void scan_sums(int* __restrict__ bsums) {
    __shared__ int tmp[1024];
    int t = threadIdx.x;
    int v = (t < SCAN_NB) ? bsums[t] : 0;
    tmp[t] = v;
    __syncthreads();
#pragma unroll
    for (int off = 1; off < 1024; off <<= 1) {
        int s = (t >= off) ? tmp[t - off] : 0;
        __syncthreads();
        tmp[t] += s;
        __syncthreads();
    }
    if (t < SCAN_NB) bsums[t] = tmp[t] - v;          // exclusive
}

__global__ void scan_add(int* __restrict__ starts, const int* __restrict__ bsums) {
    int idx = blockIdx.x * 256 + threadIdx.x;
    if (idx < KN) starts[idx] += bsums[blockIdx.x];
}

__global__ void csr_fill(const int* __restrict__ ei, const float* __restrict__ w,
                         const float* __restrict__ dinv,
                         int* __restrict__ starts, int2* __restrict__ edata) {
    int i = blockIdx.x * blockDim.x + threadIdx.x;
    if (i >= KD * EE) return;
    int k = i / EE, e = i - k * EE;
    const int* eik = ei + (size_t)k * 2 * EE;
    int row = eik[e], col = eik[EE + e];
    float nv = dinv[k * NN + col] * w[i] * dinv[k * NN + row];
    int pos = atomicAdd(&starts[k * NN + col], 1);
    edata[pos] = make_int2(row, __float_as_int(nv));
}

// ---------------- merged weight convert+transpose for ALL weights ----------------
#define GCN_T (LL * DD * DD)                 // 196608
#define ATT_T (LL * KD * DD * ATTD)          // 98304
#define P1_T  (DD * HH1)                     // 32768
#define P2_T  (HH1 * HH2)                    // 8192
#define WC_TOTAL (GCN_T + ATT_T + P1_T + P2_T)
__device__ __forceinline__ void wconv1(const float* __restrict__ W, u16* __restrict__ Wt,
                                       int i, int Kd, int Nc) {
    int kk = i / Nc, n = i - kk * Nc;
    Wt[(size_t)n * Kd + kk] = f2bf(W[i]);
}
__global__ void wconv_all(const float* __restrict__ gcnW, u16* __restrict__ gcnWb,
                          const float* __restrict__ attW, u16* __restrict__ attWb,
                          const float* __restrict__ pW1, u16* __restrict__ pW1b,
                          const float* __restrict__ pW2, u16* __restrict__ pW2b) {
    int gid = blockIdx.x * 256 + threadIdx.x;
    if (gid >= WC_TOTAL) return;
    if (gid < GCN_T) {
        int l = gid >> 16, i = gid & 65535;
        wconv1(gcnW + (size_t)l * DD * DD, gcnWb + (size_t)l * DD * DD, i, DD, DD);
    } else if (gid < GCN_T + ATT_T) {
        int g = gid - GCN_T;
        int lk = g >> 14, i = g & 16383;
        wconv1(attW + (size_t)lk * DD * ATTD, attWb + (size_t)lk * ATTD * DD, i, DD, ATTD);
    } else if (gid < GCN_T + ATT_T + P1_T) {
        wconv1(pW1, pW1b, gid - (GCN_T + ATT_T), DD, HH1);
    } else {
        wconv1(pW2, pW2b, gid - (GCN_T + ATT_T + P1_T), HH1, HH2);
    }
}

// ---------------- fold gcn_b into attention bias ----------------
__global__ void att_bias_fold(const float* __restrict__ attW, const float* __restrict__ attb,
                              const float* __restrict__ gcnb, float* __restrict__ batt) {
    int lk = blockIdx.x;          // 0..5
    int a = threadIdx.x;          // 0..63
    int l = lk >> 1;
    const float* W = attW + (size_t)lk * DD * ATTD;
    const float* gb = gcnb + l * DD;
    float s = attb[lk * ATTD + a];
    for (int d = 0; d < DD; ++d) s += gb[d] * W[d * ATTD + a];
    batt[lk * ATTD + a] = s;
}

#define LDSP 40   // LDS row stride in u16 (32 + 8 pad)

// ---------------- MFMA GEMM, BM=64, 4 waves laid out 1x4 across columns ----------------
template<int BN_, int MODE, bool PRESPLIT, bool BIAS, int ACT>
__global__ __launch_bounds__(256) void gemm_mfma(
        const float* __restrict__ A,
        const u16* __restrict__ Ahi, const u16* __restrict__ Alo,
        const u16* __restrict__ Bt, const float* __restrict__ bias,
        float* __restrict__ Cf, u16* __restrict__ Cb,
        int M, int Kd, int Nc) {
    constexpr int JW = BN_ / 64;           // j-frags per wave (wave covers BN_/4 cols)
    __shared__ u16 AsHi[64 * LDSP];
    __shared__ u16 AsLo[64 * LDSP];
    __shared__ u16 Bs[BN_ * LDSP];

    const int tid = threadIdx.x;
    const int lane = tid & 63, wx = tid >> 6;      // wave id 0..3 across columns
    const int lane15 = lane & 15, quad = lane >> 4;
    const int bm = blockIdx.x * 64;
    const int bn = blockIdx.y * BN_;

    floatx4 acc[4][JW];
#pragma unroll
    for (int i = 0; i < 4; ++i)
#pragma unroll
        for (int j = 0; j < JW; ++j) acc[i][j] = (floatx4){0.f, 0.f, 0.f, 0.f};

    for (int k0 = 0; k0 < Kd; k0 += 32) {
        if constexpr (PRESPLIT) {
            {   // 64 rows x 32 u16 per plane = 256 uint4 each; 1 per thread
                int m = tid >> 2, ko = (tid & 3) << 3;
                uint4 vh = make_uint4(0, 0, 0, 0), vl = make_uint4(0, 0, 0, 0);
                if (bm + m < M) {
                    vh = *(const uint4*)(Ahi + (size_t)(bm + m) * Kd + k0 + ko);
                    vl = *(const uint4*)(Alo + (size_t)(bm + m) * Kd + k0 + ko);
                }
                *(uint4*)(void*)(AsHi + m * LDSP + ko) = vh;
                *(uint4*)(void*)(AsLo + m * LDSP + ko) = vl;
            }
        } else {
#pragma unroll
            for (int t = tid; t < 512; t += 256) {
                int m = t >> 3, k4 = (t & 7) << 2;
                float4 v = make_float4(0.f, 0.f, 0.f, 0.f);
                if (bm + m < M) v = *(const float4*)(A + (size_t)(bm + m) * Kd + k0 + k4);
                u16 h0 = f2bf(v.x), h1 = f2bf(v.y), h2 = f2bf(v.z), h3 = f2bf(v.w);
                *(ushort4*)(void*)(AsHi + m * LDSP + k4) = make_ushort4(h0, h1, h2, h3);
                u16 l0 = f2bf(v.x - bf2f(h0)), l1 = f2bf(v.y - bf2f(h1));
                u16 l2 = f2bf(v.z - bf2f(h2)), l3 = f2bf(v.w - bf2f(h3));
                *(ushort4*)(void*)(AsLo + m * LDSP + k4) = make_ushort4(l0, l1, l2, l3);
            }
        }
#pragma unroll
        for (int t = tid; t < BN_ * 4; t += 256) {
            int n = t >> 2, ko = (t & 3) << 3;
            uint4 w = *(const uint4*)(Bt + (size_t)(bn + n) * Kd + k0 + ko);
            *(uint4*)(void*)(Bs + n * LDSP + ko) = w;
        }
        __syncthreads();

        const u16* pA  = AsHi + lane15 * LDSP + quad * 8;
        const u16* pAl = AsLo + lane15 * LDSP + quad * 8;
        const u16* pB  = Bs + (wx * (BN_ / 4) + lane15) * LDSP + quad * 8;
        short8 b[JW];
#pragma unroll
        for (int j = 0; j < JW; ++j) b[j] = *(const short8*)(pB + j * 16 * LDSP);
#pragma unroll
        for (int i = 0; i < 4; ++i) {
            short8 a = *(const short8*)(pA + i * 16 * LDSP);
#pragma unroll
            for (int j = 0; j < JW; ++j)
                acc[i][j] = __builtin_amdgcn_mfma_f32_16x16x32_bf16(a, b[j], acc[i][j], 0, 0, 0);
        }
#pragma unroll
        for (int i = 0; i < 4; ++i) {
            short8 a = *(const short8*)(pAl + i * 16 * LDSP);
#pragma unroll
            for (int j = 0; j < JW; ++j)
                acc[i][j] = __builtin_amdgcn_mfma_f32_16x16x32_bf16(a, b[j], acc[i][j], 0, 0, 0);
        }
        __syncthreads();
    }

#pragma unroll
    for (int i = 0; i < 4; ++i) {
#pragma unroll
        for (int r = 0; r < 4; ++r) {
            int row = bm + i * 16 + quad * 4 + r;
            if (row >= M) continue;
#pragma unroll
            for (int j = 0; j < JW; ++j) {
                int col = bn + wx * (BN_ / 4) + j * 16 + lane15;
                float v = acc[i][j][r];
                if constexpr (BIAS) v += bias[col];
                if constexpr (ACT == 1) v = v > 0.f ? v : SLOPE * v;
                if constexpr (MODE == 0) Cf[(size_t)row * Nc + col] = v;
                else                     Cb[(size_t)row * Nc + col] = f2bf(v);
            }
        }
    }
}

// ---------------- FUSED gather + attention v2 ----------------
// Round-10 PMC: 147 us, occ 28.5% (44.5 KB LDS -> 3 blk/CU), HBM 2.0 TB/s —
// gather starved of waves (96 chains/CU vs standalone 152). Fixes:
// (a) B-operands from global (L2-hot 64 KB) -> Bs deleted, ZERO barriers in
//     the K-loop (As is read-only after phase 1), LDS 34.3 KB -> 4 blk/CU.
// (b) gather interleaves 2 CSR-adjacent nodes per half-wave: 8 loads in
//     flight -> 16 waves x 2 halves x 8 = 256 chains/CU.
#define BMF 32
#define ALDS 264   // full-row stride in u16 (16B-aligned rows)

__global__ __launch_bounds__(256) void att_fused(
        const int* __restrict__ starts, const int2* __restrict__ edata,
        const u16* __restrict__ xw, const u16* __restrict__ Bt,
        const float* __restrict__ batt, const float* __restrict__ qv,
        const float* __restrict__ gcnb,
        u16* __restrict__ h_hi, u16* __restrict__ h_lo) {
    __shared__ u16 As[KD * BMF * ALDS];          // 33792 B
    __shared__ float simbuf[KD][2][BMF];         // 512 B

    const int tid = threadIdx.x;
    const int lane = tid & 63, waveid = tid >> 6;
    const int l32 = tid & 31;
    const int hid = tid >> 5;                    // half-wave 0..7
    const int base = lane & 32;                  // shfl base of own half
    const int bm = blockIdx.x * BMF;             // NN % BMF == 0: no tail

    // ---- phase 1: gather 64 node-rows into As, 2 nodes interleaved ----
    {
        const int kk = hid >> 2;                 // halves 0-3: k=0, 4-7: k=1
        const int r0 = (hid & 3) * 8;            // 8 rows per half
        const int widx0 = kk * NN + bm + r0;
        int sv = 0;
        if (l32 < 9) {
            int idx = widx0 - 1 + l32;
            sv = idx >= 0 ? starts[idx] : 0;     // starts[i] = end_i (post csr_fill)
        }
        int2 ed[8];
#pragma unroll
        for (int g = 0; g < 8; ++g) {
            int b = __shfl(sv, base + g), e = __shfl(sv, base + g + 1);
            ed[g] = (l32 < e - b) ? edata[b + l32] : make_int2(0, 0);
        }
#pragma unroll
        for (int g = 0; g < 8; g += 2) {
            int bA = __shfl(sv, base + g),     eA = __shfl(sv, base + g + 1);
            int eB = __shfl(sv, base + g + 2);
            int bB = eA;                          // CSR windows are adjacent
            int dA = eA - bA, dB = eB - bB;
            int mA = dA > 32 ? 32 : dA, mB = dB > 32 ? 32 : dB;
            float4 xa0 = make_float4(0.f,0.f,0.f,0.f), xa1 = make_float4(0.f,0.f,0.f,0.f);
            float4 xb0 = make_float4(0.f,0.f,0.f,0.f), xb1 = make_float4(0.f,0.f,0.f,0.f);
            int j = 0;
            // joint: 4 loads per node, 8 in flight
            for (; j + 4 <= mA && j + 4 <= mB; j += 4) {
                int ra0 = __shfl(ed[g].x, base + j),     ra1 = __shfl(ed[g].x, base + j + 1);
                int ra2 = __shfl(ed[g].x, base + j + 2), ra3 = __shfl(ed[g].x, base + j + 3);
                int rb0 = __shfl(ed[g+1].x, base + j),     rb1 = __shfl(ed[g+1].x, base + j + 1);
                int rb2 = __shfl(ed[g+1].x, base + j + 2), rb3 = __shfl(ed[g+1].x, base + j + 3);
                float na0 = __int_as_float(__shfl(ed[g].y, base + j));
                float na1 = __int_as_float(__shfl(ed[g].y, base + j + 1));
                float na2 = __int_as_float(__shfl(ed[g].y, base + j + 2));
                float na3 = __int_as_float(__shfl(ed[g].y, base + j + 3));
                float nb0 = __int_as_float(__shfl(ed[g+1].y, base + j));
                float nb1 = __int_as_float(__shfl(ed[g+1].y, base + j + 1));
                float nb2 = __int_as_float(__shfl(ed[g+1].y, base + j + 2));
                float nb3 = __int_as_float(__shfl(ed[g+1].y, base + j + 3));
                uint4 wa0 = *(const uint4*)(xw + (size_t)ra0 * DD + l32 * 8);
                uint4 wa1 = *(const uint4*)(xw + (size_t)ra1 * DD + l32 * 8);
                uint4 wa2 = *(const uint4*)(xw + (size_t)ra2 * DD + l32 * 8);
                uint4 wa3 = *(const uint4*)(xw + (size_t)ra3 * DD + l32 * 8);
                uint4 wb0 = *(const uint4*)(xw + (size_t)rb0 * DD + l32 * 8);
                uint4 wb1 = *(const uint4*)(xw + (size_t)rb1 * DD + l32 * 8);
                uint4 wb2 = *(const uint4*)(xw + (size_t)rb2 * DD + l32 * 8);
                uint4 wb3 = *(const uint4*)(xw + (size_t)rb3 * DD + l32 * 8);
                fma_row8_(xa0, xa1, wa0, na0);
                fma_row8_(xa0, xa1, wa1, na1);
                fma_row8_(xa0, xa1, wa2, na2);
                fma_row8_(xa0, xa1, wa3, na3);
                fma_row8_(xb0, xb1, wb0, nb0);
                fma_row8_(xb0, xb1, wb1, nb1);
                fma_row8_(xb0, xb1, wb2, nb2);
                fma_row8_(xb0, xb1, wb3, nb3);
            }
            int jb = j;
            // node-A tail
            for (; j + 4 <= mA; j += 4) {
                int ra0 = __shfl(ed[g].x, base + j),     ra1 = __shfl(ed[g].x, base + j + 1);
                int ra2 = __shfl(ed[g].x, base + j + 2), ra3 = __shfl(ed[g].x, base + j + 3);
                float na0 = __int_as_float(__shfl(ed[g].y, base + j));
                float na1 = __int_as_float(__shfl(ed[g].y, base + j + 1));
                float na2 = __int_as_float(__shfl(ed[g].y, base + j + 2));
                float na3 = __int_as_float(__shfl(ed[g].y, base + j + 3));
                uint4 wa0 = *(const uint4*)(xw + (size_t)ra0 * DD + l32 * 8);
                uint4 wa1 = *(const uint4*)(xw + (size_t)ra1 * DD + l32 * 8);
                uint4 wa2 = *(const uint4*)(xw + (size_t)ra2 * DD + l32 * 8);
                uint4 wa3 = *(const uint4*)(xw + (size_t)ra3 * DD + l32 * 8);
                fma_row8_(xa0, xa1, wa0, na0);
                fma_row8_(xa0, xa1, wa1, na1);
                fma_row8_(xa0, xa1, wa2, na2);
                fma_row8_(xa0, xa1, wa3, na3);
            }
            for (; j < mA; ++j) {
                int r = __shfl(ed[g].x, base + j);
                float nv = __int_as_float(__shfl(ed[g].y, base + j));
                uint4 w = *(const uint4*)(xw + (size_t)r * DD + l32 * 8);
                fma_row8_(xa0, xa1, w, nv);
            }
            // node-B tail
            for (; jb + 4 <= mB; jb += 4) {
                int rb0 = __shfl(ed[g+1].x, base + jb),     rb1 = __shfl(ed[g+1].x, base + jb + 1);
                int rb2 = __shfl(ed[g+1].x, base + jb + 2), rb3 = __shfl(ed[g+1].x, base + jb + 3);
                float nb0 = __int_as_float(__shfl(ed[g+1].y, base + jb));
                float nb1 = __int_as_float(__shfl(ed[g+1].y, base + jb + 1));
                float nb2 = __int_as_float(__shfl(ed[g+1].y, base + jb + 2));
                float nb3 = __int_as_float(__shfl(ed[g+1].y, base + jb + 3));
                uint4 wb0 = *(const uint4*)(xw + (size_t)rb0 * DD + l32 * 8);
                uint4 wb1 = *(const uint4*)(xw + (size_t)rb1 * DD + l32 * 8);
                uint4 wb2 = *(const uint4*)(xw + (size_t)rb2 * DD + l32 * 8);
                uint4 wb3 = *(const uint4*)(xw + (size_t)rb3 * DD + l32 * 8);
                fma_row8_(xb0, xb1, wb0, nb0);
                fma_row8_(xb0, xb1, wb1, nb1);
                fma_row8_(xb0, xb1, wb2, nb2);
                fma_row8_(xb0, xb1, wb3, nb3);
            }
            for (; jb < mB; ++jb) {
                int r = __shfl(ed[g+1].x, base + jb);
                float nv = __int_as_float(__shfl(ed[g+1].y, base + jb));
                uint4 w = *(const uint4*)(xw + (size_t)r * DD + l32 * 8);
                fma_row8_(xb0, xb1, w, nv);
            }
            for (int e2 = bA + 32; e2 < eA; ++e2) {      // rare: degA > 32
                int2 ee = edata[e2];
                float nv = __int_as_float(ee.y);
                uint4 w = *(const uint4*)(xw + (size_t)ee.x * DD + l32 * 8);
                fma_row8_(xa0, xa1, w, nv);
            }
            for (int e2 = bB + 32; e2 < eB; ++e2) {      // rare: degB > 32
                int2 ee = edata[e2];
                float nv = __int_as_float(ee.y);
                uint4 w = *(const uint4*)(xw + (size_t)ee.x * DD + l32 * 8);
                fma_row8_(xb0, xb1, w, nv);
            }
            u32x4 st;
            st.x = (u32)f2bf(xa0.x) | ((u32)f2bf(xa0.y) << 16);
            st.y = (u32)f2bf(xa0.z) | ((u32)f2bf(xa0.w) << 16);
            st.z = (u32)f2bf(xa1.x) | ((u32)f2bf(xa1.y) << 16);
            st.w = (u32)f2bf(xa1.z) | ((u32)f2bf(xa1.w) << 16);
            *(u32x4*)(void*)(As + (kk * BMF + r0 + g) * ALDS + l32 * 8) = st;
            st.x = (u32)f2bf(xb0.x) | ((u32)f2bf(xb0.y) << 16);
            st.y = (u32)f2bf(xb0.z) | ((u32)f2bf(xb0.w) << 16);
            st.z = (u32)f2bf(xb1.x) | ((u32)f2bf(xb1.y) << 16);
            st.w = (u32)f2bf(xb1.z) | ((u32)f2bf(xb1.w) << 16);
            *(u32x4*)(void*)(As + (kk * BMF + r0 + g + 1) * ALDS + l32 * 8) = st;
        }
    }
    __syncthreads();

    // ---- phase 2: MFMA — A from As (read-only), B from global (L2-hot), NO barriers ----
    const int kw = waveid >> 1, ch = waveid & 1;
    const int lane15 = lane & 15, quad = lane >> 4;
    floatx4 acc[2][2];
#pragma unroll
    for (int i = 0; i < 2; ++i)
#pragma unroll
        for (int j = 0; j < 2; ++j) acc[i][j] = (floatx4){0.f, 0.f, 0.f, 0.f};

    const u16* pB0 = Bt + (size_t)kw * ATTD * DD + (size_t)(ch * 32 + lane15) * DD + quad * 8;
    const u16* pB1 = pB0 + 16 * DD;
#pragma unroll
    for (int k0 = 0; k0 < DD; k0 += 32) {
        short8 b0 = *(const short8*)(pB0 + k0);
        short8 b1 = *(const short8*)(pB1 + k0);
        const u16* pA = As + (kw * BMF + lane15) * ALDS + k0 + quad * 8;
#pragma unroll
        for (int i = 0; i < 2; ++i) {
            short8 a = *(const short8*)(pA + i * 16 * ALDS);
            acc[i][0] = __builtin_amdgcn_mfma_f32_16x16x32_bf16(a, b0, acc[i][0], 0, 0, 0);
            acc[i][1] = __builtin_amdgcn_mfma_f32_16x16x32_bf16(a, b1, acc[i][1], 0, 0, 0);
        }
    }

    // ---- phase 3: sim (tanh + q dot, 4-lane-group reduce) ----
#pragma unroll
    for (int i = 0; i < 2; ++i) {
#pragma unroll
        for (int r = 0; r < 4; ++r) {
            float p = 0.f;
#pragma unroll
            for (int j = 0; j < 2; ++j) {
                int col = ch * 32 + j * 16 + lane15;
                float v = acc[i][j][r] + batt[kw * ATTD + col];
                float ex = __expf(2.f * v);
                float th = 1.f - 2.f / (ex + 1.f);     // tanh, inf-safe
                p += th * qv[kw * ATTD + col];
            }
            p += __shfl_xor(p, 1, 64);
            p += __shfl_xor(p, 2, 64);
            p += __shfl_xor(p, 4, 64);
            p += __shfl_xor(p, 8, 64);
            if (lane15 == 0) simbuf[kw][ch][i * 16 + quad * 4 + r] = p;
        }
    }
    __syncthreads();

    // ---- phase 4: combine (softmax over k, relu, split) — xs from LDS ----
#pragma unroll
    for (int it = 0; it < 4; ++it) {
        int item = tid + it * 256;
        int row = item >> 5, c8 = item & 31;
        int grow = bm + row;
        float s0 = simbuf[0][0][row] + simbuf[0][1][row];
        float s1 = simbuf[1][0][row] + simbuf[1][1][row];
        float m = fmaxf(s0, s1);
        float e0 = __expf(s0 - m), e1 = __expf(s1 - m);
        float inv = 1.f / (e0 + e1);
        float a0 = e0 * inv, a1 = e1 * inv;
        uint4 x0 = *(const uint4*)(As + row * ALDS + c8 * 8);
        uint4 x1 = *(const uint4*)(As + (BMF + row) * ALDS + c8 * 8);
        const float* bp = gcnb + c8 * 8;
        uint4 hiw, low;
        u16* hp = (u16*)&hiw; u16* lp = (u16*)&low;
        const u32* xp0 = (const u32*)&x0; const u32* xp1 = (const u32*)&x1;
#pragma unroll
        for (int j = 0; j < 4; ++j) {
            float2 f0 = __bfloat1622float2(*(const __hip_bfloat162*)&xp0[j]);
            float2 f1 = __bfloat1622float2(*(const __hip_bfloat162*)&xp1[j]);
            float ra = fmaxf(0.f, a0 * f0.x + a1 * f1.x + bp[2 * j]);
            float rb = fmaxf(0.f, a0 * f0.y + a1 * f1.y + bp[2 * j + 1]);
            u16 ha = f2bf(ra), hb = f2bf(rb);
            hp[2 * j] = ha; hp[2 * j + 1] = hb;
            lp[2 * j] = f2bf(ra - bf2f(ha));
            lp[2 * j + 1] = f2bf(rb - bf2f(hb));
        }
        *(uint4*)(h_hi + (size_t)grow * DD + c8 * 8) = hiw;
        *(uint4*)(h_lo + (size_t)grow * DD + c8 * 8) = low;
    }
}

extern "C" void kernel_launch(void* const* d_in, const int* in_sizes, int n_in,
                              void* d_out, int out_size, void* d_ws, size_t ws_size,
                              hipStream_t stream) {
    const float* x     = (const float*)d_in[0];
    const int*   ei    = (const int*)d_in[1];
    const float* ew    = (const float*)d_in[2];
    const float* gamma = (const float*)d_in[3];
    const float* beta  = (const float*)d_in[4];
    const float* gcn_W = (const float*)d_in[5];
    const float* gcn_b = (const float*)d_in[6];
    const float* att_W = (const float*)d_in[7];
    const float* att_b = (const float*)d_in[8];
    const float* att_q = (const float*)d_in[9];
    const float* pW1   = (const float*)d_in[10];
    const float* pb1   = (const float*)d_in[11];
    const float* pW2   = (const float*)d_in[12];
    const float* pb2   = (const float*)d_in[13];
    float* out = (float*)d_out;

    char* wsb = (char*)d_ws;
    size_t off = 0;
    auto alloc = [&](size_t bytes) -> void* {
        void* p = wsb + off;
        off += (bytes + 255) & ~(size_t)255;
        return p;
    };
    u16*   h_hi  = (u16*)alloc((size_t)NN * DD * 2);          // 51.2 MB
    u16*   h_lo  = (u16*)alloc((size_t)NN * DD * 2);          // 51.2 MB
    u16*   xw    = (u16*)alloc((size_t)NN * DD * 2);          // 51.2 MB
    float* p1tmp = (float*)xw;                                // N*H1*4, exact reuse
    float* dinv  = (float*)alloc((size_t)KN * 4);
    int*   starts= (int*)alloc(((size_t)KN + 1) * 4);
    u64*   dc    = (u64*)alloc((size_t)KN * 8);               // packed deg+count
    int2*  edata = (int2*)alloc((size_t)KD * EE * 8);         // 6.4 MB
    float* bnsums= (float*)alloc(2 * DD * 4);
    u16*   gcnWb = (u16*)alloc((size_t)LL * DD * DD * 2);
    u16*   attWb = (u16*)alloc((size_t)LL * KD * ATTD * DD * 2);
    u16*   pW1b  = (u16*)alloc((size_t)HH1 * DD * 2);
    u16*   pW2b  = (u16*)alloc((size_t)HH2 * HH1 * 2);
    float* batt  = (float*)alloc((size_t)LL * KD * ATTD * 4);
    int*   bsums = (int*)alloc((size_t)SCAN_NB * 4);

    // ---- setup: all weight converts in ONE kernel + att bias fold ----
    wconv_all<<<(WC_TOTAL + 255) / 256, 256, 0, stream>>>(
        gcn_W, gcnWb, att_W, attWb, pW1, pW1b, pW2, pW2b);
    att_bias_fold<<<LL * KD, ATTD, 0, stream>>>(att_W, att_b, gcn_b, batt);

    // ---- BatchNorm -> h (pre-split) ----
    hipMemsetAsync(bnsums, 0, 2 * DD * 4, stream);
    bn_stats<<<800, 256, 0, stream>>>(x, bnsums);
    bn_apply<<<25000, 256, 0, stream>>>(x, bnsums, gamma, beta, h_hi, h_lo);

    // ---- degree / CSR (layer-invariant); single packed-atomic pass ----
    hipMemsetAsync(dc, 0, (size_t)KN * 8, stream);
    deg_count<<<(KD * EE + 255) / 256, 256, 0, stream>>>(ei, ew, dc);
    dinv_pack<<<(KN + 255) / 256, 256, 0, stream>>>(dc, dinv, starts);
    scan_blocks<<<SCAN_NB, 256, 0, stream>>>(starts, bsums);
    scan_sums<<<1, 1024, 0, stream>>>(bsums);
    scan_add<<<SCAN_NB, 256, 0, stream>>>(starts, bsums);
    csr_fill<<<(KD * EE + 255) / 256, 256, 0, stream>>>(ei, ew, dinv, starts, edata);

    const int MB64 = (NN + 63) / 64;     // 1563
    const int MBF  = NN / BMF;           // 3125 exact
    for (int l = 0; l < LL; ++l) {
        // xw(bf16) = h @ gcn_W[l] — BM=64 x BN=256, copy-only staging
        gemm_mfma<256, 1, true, false, 0><<<dim3(MB64, 1), 256, 0, stream>>>(
            nullptr, h_hi, h_lo, gcnWb + (size_t)l * DD * DD, nullptr,
            nullptr, xw, NN, DD, DD);
        att_fused<<<MBF, 256, 0, stream>>>(
            starts, edata, xw, attWb + (size_t)l * KD * ATTD * DD,
            batt + (size_t)l * KD * ATTD, att_q + (size_t)l * KD * ATTD,
            gcn_b + l * DD, h_hi, h_lo);
    }

    // ---- projection head ----
    gemm_mfma<128, 0, true, true, 1><<<dim3(MB64, 1), 256, 0, stream>>>(
        nullptr, h_hi, h_lo, pW1b, pb1, p1tmp, nullptr, NN, DD, HH1);
    gemm_mfma<64, 0, false, true, 1><<<dim3(MB64, 1), 256, 0, stream>>>(
        p1tmp, nullptr, nullptr, pW2b, pb2, out, nullptr, NN, HH1, HH2);
}